// Round 9
// baseline (727.865 us; speedup 1.0000x reference)
//
#include <hip/hip_runtime.h>
#include <math.h>

#define BGR 256        // graphs
#define NPG0 400       // nodes per graph
#define NN (BGR*NPG0)  // 102400 nodes
#define NE (NN*16)     // 1638400 edges
#define HD 128
#define AST4 208       // u4 adjacency row stride BYTES (416 nibbles = 13*32)
#define A32PG (NPG0*52) // u32 words per graph u4-adjacency slice = 20800
#define KSA 13         // agg k-steps (13*32 = 416)
#define MSTR 136       // LDS row stride (shorts), 16B-aligned
#define NTPB 5         // node-tiles (of 16) per tile; 5 tiles cover a graph
#define SCGRID 2048    // wide-kernel grid
#define ACH4 1040      // adjacency tile uint4 chunks (80*208/16)
#define LGRID 640      // layer grid (all-resident: 640 <= 256 CU * 3 blocks)

typedef __attribute__((ext_vector_type(8))) short short8;
typedef __attribute__((ext_vector_type(4))) float floatx4;
typedef __attribute__((ext_vector_type(4))) unsigned int uintx4;

__device__ __forceinline__ unsigned short f2b(float f) {
    unsigned int u = __builtin_bit_cast(unsigned int, f);
    unsigned int r = (u + 0x7fffu + ((u >> 16) & 1u)) >> 16;
    return (unsigned short)r;
}
__device__ __forceinline__ unsigned int pk2(float a, float b) {
    return (unsigned int)f2b(a) | ((unsigned int)f2b(b) << 16);
}
__device__ __forceinline__ float b2f_lo(unsigned int u) { return __builtin_bit_cast(float, u << 16); }
__device__ __forceinline__ float b2f_hi(unsigned int u) { return __builtin_bit_cast(float, u & 0xffff0000u); }
__device__ __forceinline__ short bfint(unsigned int v) {
    // exact bf16 of small nonneg int (v < 256)
    return (short)(__builtin_bit_cast(unsigned int, (float)v) >> 16);
}
__device__ __forceinline__ unsigned int pkb(short a, short b) {
    return (unsigned int)(unsigned short)a | ((unsigned int)(unsigned short)b << 16);
}
// u4 decode via LDS LUT: byte -> 2 packed bf16 (bit-identical to bfint path)
__device__ __forceinline__ short8 lutdec(unsigned int u, const unsigned int* lut) {
    uintx4 w;
    w[0] = lut[u & 0xFFu];
    w[1] = lut[(u >> 8) & 0xFFu];
    w[2] = lut[(u >> 16) & 0xFFu];
    w[3] = lut[u >> 24];
    return __builtin_bit_cast(short8, w);
}
// 8-nibble dot with an LDS float vector (broadcast reads)
__device__ __forceinline__ float nibdot(unsigned int u, const float* v) {
    return (float)(u & 0xFu) * v[0] + (float)((u >> 4) & 0xFu) * v[1]
         + (float)((u >> 8) & 0xFu) * v[2] + (float)((u >> 12) & 0xFu) * v[3]
         + (float)((u >> 16) & 0xFu) * v[4] + (float)((u >> 20) & 0xFu) * v[5]
         + (float)((u >> 24) & 0xFu) * v[6] + (float)(u >> 28) * v[7];
}

// ---------------- per-graph build: LDS-atomic u4 adjacency + alive/rliv (512 thr) ----------------
__global__ __launch_bounds__(512) void k_graph2(const int* __restrict__ src,
                                                const int* __restrict__ dst,
                                                unsigned int* __restrict__ A,
                                                float* __restrict__ alive,
                                                float* __restrict__ rliv) {
    __shared__ unsigned int sA[A32PG];   // 83.2 KB
    int g = blockIdx.x, t = threadIdx.x;
    {
        uint4 z = {0u, 0u, 0u, 0u};
        uint4* s4 = (uint4*)sA;
        for (int i = t; i < A32PG / 4; i += 512) s4[i] = z;
    }
    __syncthreads();
    int ebase = g * (NPG0 * 16);
    int gb = g * NPG0;
    for (int i = t; i < NPG0 * 16; i += 512) {
        int s = src[ebase + i] - gb;
        int d = dst[ebase + i] - gb;
        int nib = d * 416 + s;
        atomicAdd(&sA[nib >> 3], 1u << ((nib & 7) * 4));
    }
    __syncthreads();
    {
        uint4* Ao = (uint4*)(A + (long)g * A32PG);
        const uint4* si = (const uint4*)sA;
        for (int i = t; i < A32PG / 4; i += 512) Ao[i] = si[i];
    }
    for (int n = t; n < NPG0; n += 512) {
        const unsigned int* row = &sA[n * 52];
        unsigned int deg = 0;
        for (int c = 0; c < 52; ++c) {
            unsigned int u = row[c];
            unsigned int p = (u & 0x0F0F0F0Fu) + ((u >> 4) & 0x0F0F0F0Fu);
            deg += (p * 0x01010101u) >> 24;
        }
        alive[gb + n] = 1.0f;
        rliv[gb + n] = 1.0f / fmaxf((float)deg, 1.0f);
    }
}

// ---------------- W -> bf16, transposed: bt[m][j*128 + f] = bf16(W_m[f*128 + j]) = W^T row-major
__global__ void k_wcvt(const float* __restrict__ c1_wr, const float* __restrict__ c1_ws,
                       const float* __restrict__ cs_wr, const float* __restrict__ cs_ws,
                       unsigned short* __restrict__ bt) {
    int m = blockIdx.y;
    int idx = blockIdx.x * 256 + threadIdx.x;
    const float* W = (m == 0) ? c1_wr : (m == 1) ? c1_ws
                   : (m < 6) ? (cs_wr + (m - 2) * HD * HD) : (cs_ws + (m - 6) * HD * HD);
    int n = idx >> 7, k = idx & 127;
    bt[m * HD * HD + idx] = f2b(W[k * HD + n]);
}

// ---------------- one-time input transpose: x_in fp32 [NN][128] -> xT bf16 [128][NN]
__global__ __launch_bounds__(512) void k_xt0(const float* __restrict__ xin,
                                             unsigned short* __restrict__ xt) {
    int t = threadIdx.x;
    int ngrp = blockIdx.x * 128 + (t >> 2);   // node group (4 nodes)
    int j = t & 3;
    int r0 = ngrp * 4;
    int f0 = blockIdx.y * 4;                  // feature group (4 feats)
    float4 v = ((const float4*)xin)[(long)(r0 + j) * 32 + (f0 >> 2)];
    float a0 = v.x, a1 = v.y, a2 = v.z, a3 = v.w;
    float tw;
    bool bo1 = j & 1;
    tw = __shfl_xor(bo1 ? a0 : a1, 1); if (bo1) a0 = tw; else a1 = tw;
    tw = __shfl_xor(bo1 ? a2 : a3, 1); if (bo1) a2 = tw; else a3 = tw;
    bool bo2 = (j & 2) != 0;
    tw = __shfl_xor(bo2 ? a0 : a2, 2); if (bo2) a0 = tw; else a2 = tw;
    tw = __shfl_xor(bo2 ? a1 : a3, 2); if (bo2) a1 = tw; else a3 = tw;
    uint2 w; w.x = pk2(a0, a1); w.y = pk2(a2, a3);
    *(uint2*)&xt[(long)(f0 + j) * NN + r0] = w;
}

// ---------------- wide rescale: xT (feature-major) *= mult[node]
__global__ __launch_bounds__(256) void k_scale(unsigned short* __restrict__ xt,
                                               const float* __restrict__ multg)
{
    int tid = blockIdx.x * 256 + threadIdx.x;
    const int step = SCGRID * 256;
    for (int i = tid; i < HD * (NN / 4); i += step) {
        int f = i / (NN / 4), c = i - f * (NN / 4);
        int n4 = c * 4;
        unsigned short* p = &xt[(long)f * NN + n4];
        uint2 u = *(uint2*)p, w;
        w.x = pk2(b2f_lo(u.x) * multg[n4], b2f_hi(u.x) * multg[n4 + 1]);
        w.y = pk2(b2f_lo(u.y) * multg[n4 + 2], b2f_hi(u.y) * multg[n4 + 3]);
        *(uint2*)p = w;
    }
}

// ---------------- fused layer v11: all-resident grid (640 blocks), 2 tiles per block.
//  Layer-invariant loads (LUT, W-frags, bias, pool weights) hoisted out of the tile loop.
//  Per tile: v10's pipeline — adjacency bulk-staged to LDS (aliased with sM), prologue
//  sX transpose, k-loop = LDS adjacency + LUT decode + depth-2 xT prefetch, pure-LDS phase B.
template<bool HASD, bool LAST>
__global__ __launch_bounds__(256, 3) void k_layer11(
    const unsigned short* __restrict__ xtin, unsigned short* __restrict__ xtout,
    const unsigned char* __restrict__ Amat,
    const float* __restrict__ alive, const float* __restrict__ rliv,
    const unsigned short* __restrict__ wr_bt, const unsigned short* __restrict__ ws_bt,
    const float* __restrict__ bias, float* __restrict__ hcat, int layer,
    const float* __restrict__ pwr, const float* __restrict__ pws, float* __restrict__ dd)
{
    // per tile: phase A adjacency (16.6 KB) then sM mean tile (21.8 KB), aliased
    __shared__ __align__(16) unsigned char sAM[NTPB * 16 * MSTR * 2];
    __shared__ __align__(16) unsigned short sX[NTPB * 16 * MSTR];   // x tile (node-major)
    __shared__ unsigned int sLUT[256];                              // byte -> 2 packed bf16
    int t = threadIdx.x;
    int lane = t & 63, wid = t >> 6;          // 4 waves
    int quad = lane >> 4, l15 = lane & 15;
    int mp = wid;                              // feature pair-group: m-tiles 2mp, 2mp+1
    int gi = t >> 2, j4 = t & 3;               // staging transpose group/lane

    sLUT[t] = pkb(bfint(t & 0xFu), bfint(t >> 4));

    // ---- layer-invariant: W frags, bias, pool weights (loaded ONCE per block)
    short8 Wr8[2][4], Ws8[2][4];
#pragma unroll
    for (int mt = 0; mt < 2; ++mt) {
        int jj = (2 * mp + mt) * 16 + l15;
#pragma unroll
        for (int k = 0; k < 4; ++k) {
            Wr8[mt][k] = *(const short8*)&wr_bt[jj * HD + k * 32 + quad * 8];
            Ws8[mt][k] = *(const short8*)&ws_bt[jj * HD + k * 32 + quad * 8];
        }
    }
    float4 b40 = *(const float4*)&bias[(2 * mp) * 16 + quad * 4];
    float4 b41 = *(const float4*)&bias[(2 * mp + 1) * 16 + quad * 4];
    float4 pwrA, pwrB, pwsA, pwsB;
    if (HASD) {
        pwrA = *(const float4*)&pwr[(2 * mp) * 16 + quad * 4];
        pwrB = *(const float4*)&pwr[(2 * mp + 1) * 16 + quad * 4];
        pwsA = *(const float4*)&pws[(2 * mp) * 16 + quad * 4];
        pwsB = *(const float4*)&pws[(2 * mp + 1) * 16 + quad * 4];
    }

    for (int r = 0; r < 2; ++r) {
        int tile = blockIdx.x + r * LGRID;     // 0..1279
        int g = tile & 255;
        int ntg = tile >> 8;                    // 0..4
        long gbase = (long)g * NPG0;
        int nbase = ntg * (NTPB * 16);

        // ---- issue tile loads into registers (no LDS writes yet)
        const unsigned char* Ag = Amat + (gbase + nbase) * (long)AST4;
        uint4 astg[5];
        {
            const uint4* Ag4 = (const uint4*)Ag;
#pragma unroll
            for (int c = t, rr = 0; rr < 5; ++rr, c += 256) {
                if (c < ACH4) astg[rr] = Ag4[c];
            }
        }
        uint2 stg[10];
#pragma unroll
        for (int it = 0; it < 10; ++it) {
            int tid2 = gi + it * 64;
            int fg = tid2 / 20, ng = tid2 - fg * 20;
            stg[it] = *(const uint2*)&xtin[(long)(fg * 4 + j4) * NN + gbase + nbase + ng * 4];
        }
        float rl[NTPB];
#pragma unroll
        for (int nt = 0; nt < NTPB; ++nt) rl[nt] = rliv[gbase + nbase + nt * 16 + l15];

        if (r) __syncthreads();   // previous tile's phase-B LDS reads complete

        // adjacency -> LDS
#pragma unroll
        for (int c = t, rr = 0; rr < 5; ++rr, c += 256) {
            if (c < ACH4) *(uint4*)&sAM[c * 16] = astg[rr];
        }
        // x-tile 4x4 shfl-transpose -> sX (node-major)
#pragma unroll
        for (int it = 0; it < 10; ++it) {
            int tid2 = gi + it * 64;
            int fg = tid2 / 20, ng = tid2 - fg * 20;
            uint2 u = stg[it];
            float a0 = b2f_lo(u.x), a1 = b2f_hi(u.x), a2 = b2f_lo(u.y), a3 = b2f_hi(u.y);
            float tw;
            bool bo1 = j4 & 1;
            tw = __shfl_xor(bo1 ? a0 : a1, 1); if (bo1) a0 = tw; else a1 = tw;
            tw = __shfl_xor(bo1 ? a2 : a3, 1); if (bo1) a2 = tw; else a3 = tw;
            bool bo2 = (j4 & 2) != 0;
            tw = __shfl_xor(bo2 ? a0 : a2, 2); if (bo2) a0 = tw; else a2 = tw;
            tw = __shfl_xor(bo2 ? a1 : a3, 2); if (bo2) a1 = tw; else a3 = tw;
            uint2 w; w.x = pk2(a0, a1); w.y = pk2(a2, a3);
            *(uint2*)&sX[(ng * 4 + j4) * MSTR + fg * 4] = w;
        }

        // prime depth-2 xT A-frag pipeline
        const unsigned short* xa0 = xtin + (long)(mp * 32 + l15) * NN + gbase;
        const unsigned short* xa1 = xa0 + (long)16 * NN;
        short8 Ac0 = *(const short8*)&xa0[quad * 8];
        short8 Ac1 = *(const short8*)&xa1[quad * 8];
        short8 An0 = *(const short8*)&xa0[32 + quad * 8];
        short8 An1 = *(const short8*)&xa1[32 + quad * 8];

        __syncthreads();   // sAM (adjacency) + sX + sLUT visible

        // ---- phase A: agg GEMM; adjacency from LDS + LUT, xT depth-2 prefetched
        floatx4 acc[NTPB][2];
#pragma unroll
        for (int nt = 0; nt < NTPB; ++nt) {
            acc[nt][0] = (floatx4){0.f, 0.f, 0.f, 0.f};
            acc[nt][1] = (floatx4){0.f, 0.f, 0.f, 0.f};
        }
        int abase = l15 * AST4 + quad * 4;
#pragma unroll
        for (int k = 0; k < KSA; ++k) {
            short8 Af0, Af1;
            if (k + 2 < KSA) {
                int ko = (k + 2) * 32 + quad * 8;
                Af0 = *(const short8*)&xa0[ko];
                Af1 = *(const short8*)&xa1[ko];
            }
#pragma unroll
            for (int nt = 0; nt < NTPB; ++nt) {
                unsigned int u = *(const unsigned int*)&sAM[abase + nt * (16 * AST4) + k * 16];
                short8 Bf = lutdec(u, sLUT);
                acc[nt][0] = __builtin_amdgcn_mfma_f32_16x16x32_bf16(Ac0, Bf, acc[nt][0], 0, 0, 0);
                acc[nt][1] = __builtin_amdgcn_mfma_f32_16x16x32_bf16(Ac1, Bf, acc[nt][1], 0, 0, 0);
            }
            if (k + 1 < KSA) { Ac0 = An0; Ac1 = An1; }
            if (k + 2 < KSA) { An0 = Af0; An1 = Af1; }
        }
        __syncthreads();   // all adjacency LDS reads done; sAM region becomes sM

        // ---- scale by rliv, write mean tile to sM (aliased region)
        unsigned short* sM = (unsigned short*)sAM;
#pragma unroll
        for (int nt = 0; nt < NTPB; ++nt) {
            int lo = nt * 16 + l15;
            unsigned short* mrow = &sM[lo * MSTR + 32 * mp + quad * 4];
            uint2 w0, w1;
            w0.x = pk2(acc[nt][0][0] * rl[nt], acc[nt][0][1] * rl[nt]);
            w0.y = pk2(acc[nt][0][2] * rl[nt], acc[nt][0][3] * rl[nt]);
            w1.x = pk2(acc[nt][1][0] * rl[nt], acc[nt][1][1] * rl[nt]);
            w1.y = pk2(acc[nt][1][2] * rl[nt], acc[nt][1][3] * rl[nt]);
            *(uint2*)mrow = w0;
            *(uint2*)(mrow + 16) = w1;
        }
        float av[NTPB];
#pragma unroll
        for (int nt = 0; nt < NTPB; ++nt) av[nt] = alive[gbase + nbase + nt * 16 + l15];
        __syncthreads();   // sM visible

        // ---- phase B: transposed conv, pure LDS operands
        float ps0[4] = {0, 0, 0, 0}, ps1[4] = {0, 0, 0, 0};
#pragma unroll
        for (int nt = 0; nt < NTPB; ++nt) {
            int lo = nt * 16 + l15;
            long go = gbase + nbase + lo;
            floatx4 a0 = {b40.x, b40.y, b40.z, b40.w};
            floatx4 a1 = {b41.x, b41.y, b41.z, b41.w};
#pragma unroll
            for (int k = 0; k < 4; ++k) {
                short8 B0 = *(const short8*)&sM[lo * MSTR + k * 32 + quad * 8];
                a0 = __builtin_amdgcn_mfma_f32_16x16x32_bf16(Wr8[0][k], B0, a0, 0, 0, 0);
                a1 = __builtin_amdgcn_mfma_f32_16x16x32_bf16(Wr8[1][k], B0, a1, 0, 0, 0);
            }
#pragma unroll
            for (int k = 0; k < 4; ++k) {
                short8 B1 = *(const short8*)&sX[lo * MSTR + k * 32 + quad * 8];
                a0 = __builtin_amdgcn_mfma_f32_16x16x32_bf16(Ws8[0][k], B1, a0, 0, 0, 0);
                a1 = __builtin_amdgcn_mfma_f32_16x16x32_bf16(Ws8[1][k], B1, a1, 0, 0, 0);
            }
            bool liv = av[nt] != 0.0f;
            float v0r[4], v1r[4];
#pragma unroll
            for (int rr = 0; rr < 4; ++rr) {
                v0r[rr] = fmaxf(a0[rr], 0.0f);
                v1r[rr] = fmaxf(a1[rr], 0.0f);
                if (liv) { ps0[rr] += v0r[rr]; ps1[rr] += v1r[rr]; }
                if (!liv) { v0r[rr] = 0.0f; v1r[rr] = 0.0f; }
            }
            if (!LAST) {
#pragma unroll
                for (int rr = 0; rr < 4; ++rr) {
                    xtout[(long)(32 * mp + quad * 4 + rr) * NN + go] = f2b(v0r[rr]);
                    xtout[(long)(32 * mp + 16 + quad * 4 + rr) * NN + go] = f2b(v1r[rr]);
                }
            }
            if (HASD) {
                float pr = v0r[0]*pwrA.x + v0r[1]*pwrA.y + v0r[2]*pwrA.z + v0r[3]*pwrA.w
                         + v1r[0]*pwrB.x + v1r[1]*pwrB.y + v1r[2]*pwrB.z + v1r[3]*pwrB.w;
                float pd = v0r[0]*pwsA.x + v0r[1]*pwsA.y + v0r[2]*pwsA.z + v0r[3]*pwsA.w
                         + v1r[0]*pwsB.x + v1r[1]*pwsB.y + v1r[2]*pwsB.z + v1r[3]*pwsB.w;
                pr += __shfl_xor(pr, 16); pr += __shfl_xor(pr, 32);
                pd += __shfl_xor(pd, 16); pd += __shfl_xor(pd, 32);
                if (quad == 0) {
                    float2 st = {pr, pd};
                    *(float2*)&dd[go * 8 + mp * 2] = st;
                }
            }
        }
        // fused readout: reduce over l15 (node lanes), atomic into hcat
#pragma unroll
        for (int rr = 0; rr < 4; ++rr) {
            float v = ps0[rr];
            v += __shfl_xor(v, 1); v += __shfl_xor(v, 2); v += __shfl_xor(v, 4); v += __shfl_xor(v, 8);
            float u = ps1[rr];
            u += __shfl_xor(u, 1); u += __shfl_xor(u, 2); u += __shfl_xor(u, 4); u += __shfl_xor(u, 8);
            if (l15 == 0) {
                atomicAdd(&hcat[g * (5 * HD) + layer * HD + (2 * mp) * 16 + quad * 4 + rr], v);
                atomicAdd(&hcat[g * (5 * HD) + layer * HD + (2 * mp + 1) * 16 + quad * 4 + rr], u);
            }
        }
    }
}

// ---------------- pool v3 (512 thr): dense-adjacency neighbor sums; top-K; mult/alive/rliv
__global__ __launch_bounds__(512) void k_pool2(
    const float* __restrict__ dd, const unsigned int* __restrict__ A,
    float* __restrict__ multg, float* __restrict__ alive, float* __restrict__ rliv,
    const float* __restrict__ pb, int K)
{
    __shared__ float str[NPG0];
    __shared__ float stsb[NPG0];
    __shared__ float sal[NPG0];
    __shared__ float s[512];
    __shared__ float sc[NPG0];
    __shared__ float kf[NPG0];
    __shared__ unsigned char keep[NPG0];
    __shared__ int cnt_gt;
    int g = blockIdx.x, t = threadIdx.x;
    long nb = (long)g * NPG0;
    float pbv = pb[0];

    for (int n = t; n < NPG0; n += 512) {
        const float* dp = &dd[(nb + n) * 8];
        float4 da = *(const float4*)dp;
        float4 db = *(const float4*)(dp + 4);
        str[n] = da.x + da.z + db.x + db.z;          // x @ p_wr
        stsb[n] = da.y + da.w + db.y + db.w + pbv;   // x @ p_ws + b
        sal[n] = alive[nb + n];
    }
    if (t == 0) cnt_gt = 0;
    __syncthreads();

    for (int n = t; n < 512; n += 512) {
        float v = -INFINITY;
        if (n < NPG0 && sal[n] != 0.0f) {
            const uint4* Ar = (const uint4*)(A + ((long)g * NPG0 + n) * 52);
            float ssum = 0.0f;
#pragma unroll
            for (int c = 0; c < 13; ++c) {
                uint4 q = Ar[c];
                ssum += nibdot(q.x, &str[c * 32]);
                ssum += nibdot(q.y, &str[c * 32 + 8]);
                ssum += nibdot(q.z, &str[c * 32 + 16]);
                ssum += nibdot(q.w, &str[c * 32 + 24]);
            }
            v = ssum * rliv[nb + n] + stsb[n];
        }
        s[n] = v;
        if (n < NPG0) sc[n] = v;
    }
    __syncthreads();

    for (int ksz = 2; ksz <= 512; ksz <<= 1) {
        for (int jsz = ksz >> 1; jsz >= 1; jsz >>= 1) {
            for (int i = t; i < 512; i += 512) {
                int ixj = i ^ jsz;
                if (ixj > i) {
                    float a = s[i], c = s[ixj];
                    bool up = ((i & ksz) == 0);
                    if ((a > c) == up) { s[i] = c; s[ixj] = a; }
                }
            }
            __syncthreads();
        }
    }
    float thr = s[512 - K];
    for (int n = t; n < NPG0; n += 512)
        if (sc[n] > thr) atomicAdd(&cnt_gt, 1);
    __syncthreads();
    if (t == 0) {   // tie-break: lowest index (matches lax.top_k)
        int m = K - cnt_gt, tk = 0;
        for (int n = 0; n < NPG0; n++) {
            bool kp = sc[n] > thr;
            if (!kp && sc[n] == thr && tk < m) { kp = true; tk++; }
            keep[n] = kp ? 1 : 0;
        }
    }
    __syncthreads();
    for (int n = t; n < NPG0; n += 512) {
        multg[nb + n] = keep[n] ? tanhf(sc[n]) : 0.0f;
        alive[nb + n] = keep[n] ? 1.0f : 0.0f;
        kf[n] = keep[n] ? 1.0f : 0.0f;
    }
    __syncthreads();
    for (int n = t; n < NPG0; n += 512) {
        const uint4* Ar = (const uint4*)(A + ((long)g * NPG0 + n) * 52);
        float ssum = 0.0f;
#pragma unroll
        for (int c = 0; c < 13; ++c) {
            uint4 q = Ar[c];
            ssum += nibdot(q.x, &kf[c * 32]);
            ssum += nibdot(q.y, &kf[c * 32 + 8]);
            ssum += nibdot(q.z, &kf[c * 32 + 16]);
            ssum += nibdot(q.w, &kf[c * 32 + 24]);
        }
        rliv[nb + n] = 1.0f / fmaxf(ssum, 1.0f);
    }
}

// ---------------- final MLP + log_softmax (hcat holds SUMS; divide here)
__global__ __launch_bounds__(128) void k_mlp(const float* __restrict__ h, const float* __restrict__ w1,
    const float* __restrict__ b1, const float* __restrict__ w2,
    const float* __restrict__ b2, float* __restrict__ out) {
    __shared__ float h1[HD];
    __shared__ float red[HD];
    __shared__ float lg[2];
    const float inv[5] = {1.0f/400.0f, 1.0f/400.0f, 1.0f/320.0f, 1.0f/320.0f, 1.0f/256.0f};
    int g = blockIdx.x, j = threadIdx.x;
    const float* hg = &h[g * (5 * HD)];
    float acc = b1[j];
    for (int k = 0; k < 5 * HD; k++) acc += hg[k] * inv[k >> 7] * w1[k * HD + j];
    h1[j] = fmaxf(acc, 0.0f);
    __syncthreads();
    for (int c = 0; c < 2; c++) {
        red[j] = h1[j] * w2[j * 2 + c];
        __syncthreads();
        for (int st = 64; st > 0; st >>= 1) {
            if (j < st) red[j] += red[j + st];
            __syncthreads();
        }
        if (j == 0) lg[c] = red[0] + b2[c];
        __syncthreads();
    }
    if (j == 0) {
        float l0 = lg[0], l1 = lg[1];
        float m = fmaxf(l0, l1);
        float lse = m + logf(expf(l0 - m) + expf(l1 - m));
        out[g * 2 + 0] = l0 - lse;
        out[g * 2 + 1] = l1 - lse;
    }
}

extern "C" void kernel_launch(void* const* d_in, const int* in_sizes, int n_in,
                              void* d_out, int out_size, void* d_ws, size_t ws_size,
                              hipStream_t stream) {
    const float* x_in   = (const float*)d_in[0];
    const int*   eidx   = (const int*)d_in[1];
    const int*   e_src  = eidx;
    const int*   e_dst  = eidx + NE;
    const float* c1_wr  = (const float*)d_in[3];
    const float* c1_ws  = (const float*)d_in[4];
    const float* c1_b   = (const float*)d_in[5];
    const float* cs_wr  = (const float*)d_in[6];
    const float* cs_ws  = (const float*)d_in[7];
    const float* cs_b   = (const float*)d_in[8];
    const float* p_wr   = (const float*)d_in[9];
    const float* p_ws   = (const float*)d_in[10];
    const float* p_b    = (const float*)d_in[11];
    const float* l1_w   = (const float*)d_in[12];
    const float* l1_b   = (const float*)d_in[13];
    const float* l2_w   = (const float*)d_in[14];
    const float* l2_b   = (const float*)d_in[15];
    float* out = (float*)d_out;

    char* ws = (char*)d_ws;
    size_t off = 0;
    float* alive = (float*)(ws + off);           off += (size_t)NN * 4;
    float* rliv  = (float*)(ws + off);           off += (size_t)NN * 4;
    float* hcat  = (float*)(ws + off);           off += (size_t)BGR * 5 * HD * 4;
    unsigned short* wbt = (unsigned short*)(ws + off); off += (size_t)10 * HD * HD * 2;
    unsigned int* Amat = (unsigned int*)(ws + off);    off += (size_t)NN * 52 * 4;
    unsigned short* xtA = (unsigned short*)(ws + off); off += ((size_t)NN * HD + 32) * 2;
    unsigned short* xtB = (unsigned short*)(ws + off); off += ((size_t)NN * HD + 32) * 2;
    float* dd    = (float*)(ws + off);           off += (size_t)NN * 8 * 4;
    float* multg = (float*)(ws + off);           off += (size_t)NN * 4;

    hipMemsetAsync(hcat, 0, (size_t)BGR * 5 * HD * 4, stream);
    // zero the tails so the k=12 chunk of the last graph's last feature row reads zeros
    hipMemsetAsync(xtA + (size_t)NN * HD, 0, 64, stream);
    hipMemsetAsync(xtB + (size_t)NN * HD, 0, 64, stream);

    k_graph2<<<BGR, 512, 0, stream>>>(e_src, e_dst, Amat, alive, rliv);
    k_wcvt<<<dim3(64, 10), 256, 0, stream>>>(c1_wr, c1_ws, cs_wr, cs_ws, wbt);
    k_xt0<<<dim3(200, 32), 512, 0, stream>>>(x_in, xtB);

    unsigned short* bt_wr[5] = { wbt + 0 * HD * HD, wbt + 2 * HD * HD, wbt + 3 * HD * HD, wbt + 4 * HD * HD, wbt + 5 * HD * HD };
    unsigned short* bt_ws[5] = { wbt + 1 * HD * HD, wbt + 6 * HD * HD, wbt + 7 * HD * HD, wbt + 8 * HD * HD, wbt + 9 * HD * HD };
    const unsigned char* Am8 = (const unsigned char*)Amat;

    // L0 (conv1): xtB -> xtA
    k_layer11<false, false><<<LGRID, 256, 0, stream>>>(
        xtB, xtA, Am8, alive, rliv,
        bt_wr[0], bt_ws[0], c1_b, hcat, 0, nullptr, nullptr, nullptr);
    // L1 (convs[0]) + pool0 dots: xtA -> xtB
    k_layer11<true, false><<<LGRID, 256, 0, stream>>>(
        xtA, xtB, Am8, alive, rliv,
        bt_wr[1], bt_ws[1], cs_b + 0 * HD, hcat, 1, p_wr + 0 * HD, p_ws + 0 * HD, dd);
    // pool 0 (K=320)
    k_pool2<<<BGR, 512, 0, stream>>>(dd, Amat, multg, alive, rliv, p_b + 0, 320);
    k_scale<<<SCGRID, 256, 0, stream>>>(xtB, multg);
    // L2 (convs[1]): xtB -> xtA
    k_layer11<false, false><<<LGRID, 256, 0, stream>>>(
        xtB, xtA, Am8, alive, rliv,
        bt_wr[2], bt_ws[2], cs_b + 1 * HD, hcat, 2, nullptr, nullptr, nullptr);
    // L3 (convs[2]) + pool1 dots: xtA -> xtB
    k_layer11<true, false><<<LGRID, 256, 0, stream>>>(
        xtA, xtB, Am8, alive, rliv,
        bt_wr[3], bt_ws[3], cs_b + 2 * HD, hcat, 3, p_wr + 1 * HD, p_ws + 1 * HD, dd);
    // pool 1 (K=256)
    k_pool2<<<BGR, 512, 0, stream>>>(dd, Amat, multg, alive, rliv, p_b + 1, 256);
    k_scale<<<SCGRID, 256, 0, stream>>>(xtB, multg);
    // L4 (convs[3], no x output): xtB -> (readout only)
    k_layer11<false, true><<<LGRID, 256, 0, stream>>>(
        xtB, nullptr, Am8, alive, rliv,
        bt_wr[4], bt_ws[4], cs_b + 3 * HD, hcat, 4, nullptr, nullptr, nullptr);
    // MLP head
    k_mlp<<<BGR, HD, 0, stream>>>(hcat, l1_w, l1_b, l2_w, l2_b, out);
}

// Round 10
// 543.316 us; speedup vs baseline: 1.3397x; 1.3397x over previous
//
#include <hip/hip_runtime.h>
#include <math.h>

#define BGR 256        // graphs
#define NPG0 400       // nodes per graph
#define NN (BGR*NPG0)  // 102400 nodes
#define NE (NN*16)     // 1638400 edges
#define HD 128
#define AST4 208       // u4 adjacency row stride BYTES (416 nibbles = 13*32)
#define A32PG (NPG0*52) // u32 words per graph u4-adjacency slice = 20800
#define KSA 13         // agg k-steps (13*32 = 416)
#define MSTR 136       // LDS row stride (shorts), 16B-aligned
#define NTPB 5         // node-tiles (of 16) per block; 5 blocks cover a graph
#define SCGRID 2048    // wide-kernel grid
#define ACH4 1040      // adjacency tile uint4 chunks (80*208/16)

typedef __attribute__((ext_vector_type(8))) short short8;
typedef __attribute__((ext_vector_type(4))) float floatx4;
typedef __attribute__((ext_vector_type(4))) unsigned int uintx4;

__device__ __forceinline__ unsigned short f2b(float f) {
    unsigned int u = __builtin_bit_cast(unsigned int, f);
    unsigned int r = (u + 0x7fffu + ((u >> 16) & 1u)) >> 16;
    return (unsigned short)r;
}
__device__ __forceinline__ unsigned int pk2(float a, float b) {
    return (unsigned int)f2b(a) | ((unsigned int)f2b(b) << 16);
}
__device__ __forceinline__ float b2f_lo(unsigned int u) { return __builtin_bit_cast(float, u << 16); }
__device__ __forceinline__ float b2f_hi(unsigned int u) { return __builtin_bit_cast(float, u & 0xffff0000u); }
__device__ __forceinline__ short bfint(unsigned int v) {
    // exact bf16 of small nonneg int (v < 256)
    return (short)(__builtin_bit_cast(unsigned int, (float)v) >> 16);
}
__device__ __forceinline__ unsigned int pkb(short a, short b) {
    return (unsigned int)(unsigned short)a | ((unsigned int)(unsigned short)b << 16);
}
// u4 decode via LDS LUT: byte -> 2 packed bf16 (bit-identical to bfint path)
__device__ __forceinline__ short8 lutdec(unsigned int u, const unsigned int* lut) {
    uintx4 w;
    w[0] = lut[u & 0xFFu];
    w[1] = lut[(u >> 8) & 0xFFu];
    w[2] = lut[(u >> 16) & 0xFFu];
    w[3] = lut[u >> 24];
    return __builtin_bit_cast(short8, w);
}
// 8-nibble dot with an LDS float vector (broadcast reads)
__device__ __forceinline__ float nibdot(unsigned int u, const float* v) {
    return (float)(u & 0xFu) * v[0] + (float)((u >> 4) & 0xFu) * v[1]
         + (float)((u >> 8) & 0xFu) * v[2] + (float)((u >> 12) & 0xFu) * v[3]
         + (float)((u >> 16) & 0xFu) * v[4] + (float)((u >> 20) & 0xFu) * v[5]
         + (float)((u >> 24) & 0xFu) * v[6] + (float)(u >> 28) * v[7];
}

// ---------------- per-graph build: LDS-atomic u4 adjacency + alive/rliv (512 thr) ----------------
__global__ __launch_bounds__(512) void k_graph2(const int* __restrict__ src,
                                                const int* __restrict__ dst,
                                                unsigned int* __restrict__ A,
                                                float* __restrict__ alive,
                                                float* __restrict__ rliv) {
    __shared__ unsigned int sA[A32PG];   // 83.2 KB
    int g = blockIdx.x, t = threadIdx.x;
    {
        uint4 z = {0u, 0u, 0u, 0u};
        uint4* s4 = (uint4*)sA;
        for (int i = t; i < A32PG / 4; i += 512) s4[i] = z;
    }
    __syncthreads();
    int ebase = g * (NPG0 * 16);
    int gb = g * NPG0;
    for (int i = t; i < NPG0 * 16; i += 512) {
        int s = src[ebase + i] - gb;
        int d = dst[ebase + i] - gb;
        int nib = d * 416 + s;
        atomicAdd(&sA[nib >> 3], 1u << ((nib & 7) * 4));
    }
    __syncthreads();
    {
        uint4* Ao = (uint4*)(A + (long)g * A32PG);
        const uint4* si = (const uint4*)sA;
        for (int i = t; i < A32PG / 4; i += 512) Ao[i] = si[i];
    }
    for (int n = t; n < NPG0; n += 512) {
        const unsigned int* row = &sA[n * 52];
        unsigned int deg = 0;
        for (int c = 0; c < 52; ++c) {
            unsigned int u = row[c];
            unsigned int p = (u & 0x0F0F0F0Fu) + ((u >> 4) & 0x0F0F0F0Fu);
            deg += (p * 0x01010101u) >> 24;
        }
        alive[gb + n] = 1.0f;
        rliv[gb + n] = 1.0f / fmaxf((float)deg, 1.0f);
    }
}

// ---------------- W -> bf16, transposed: bt[m][j*128 + f] = bf16(W_m[f*128 + j]) = W^T row-major
__global__ void k_wcvt(const float* __restrict__ c1_wr, const float* __restrict__ c1_ws,
                       const float* __restrict__ cs_wr, const float* __restrict__ cs_ws,
                       unsigned short* __restrict__ bt) {
    int m = blockIdx.y;
    int idx = blockIdx.x * 256 + threadIdx.x;
    const float* W = (m == 0) ? c1_wr : (m == 1) ? c1_ws
                   : (m < 6) ? (cs_wr + (m - 2) * HD * HD) : (cs_ws + (m - 6) * HD * HD);
    int n = idx >> 7, k = idx & 127;
    bt[m * HD * HD + idx] = f2b(W[k * HD + n]);
}

// ---------------- one-time input transpose: x_in fp32 [NN][128] -> xT bf16 [128][NN]
__global__ __launch_bounds__(512) void k_xt0(const float* __restrict__ xin,
                                             unsigned short* __restrict__ xt) {
    int t = threadIdx.x;
    int ngrp = blockIdx.x * 128 + (t >> 2);   // node group (4 nodes)
    int j = t & 3;
    int r0 = ngrp * 4;
    int f0 = blockIdx.y * 4;                  // feature group (4 feats)
    float4 v = ((const float4*)xin)[(long)(r0 + j) * 32 + (f0 >> 2)];
    float a0 = v.x, a1 = v.y, a2 = v.z, a3 = v.w;
    float tw;
    bool bo1 = j & 1;
    tw = __shfl_xor(bo1 ? a0 : a1, 1); if (bo1) a0 = tw; else a1 = tw;
    tw = __shfl_xor(bo1 ? a2 : a3, 1); if (bo1) a2 = tw; else a3 = tw;
    bool bo2 = (j & 2) != 0;
    tw = __shfl_xor(bo2 ? a0 : a2, 2); if (bo2) a0 = tw; else a2 = tw;
    tw = __shfl_xor(bo2 ? a1 : a3, 2); if (bo2) a1 = tw; else a3 = tw;
    uint2 w; w.x = pk2(a0, a1); w.y = pk2(a2, a3);
    *(uint2*)&xt[(long)(f0 + j) * NN + r0] = w;
}

// ---------------- wide rescale: xT (feature-major) *= mult[node]
__global__ __launch_bounds__(256) void k_scale(unsigned short* __restrict__ xt,
                                               const float* __restrict__ multg)
{
    int tid = blockIdx.x * 256 + threadIdx.x;
    const int step = SCGRID * 256;
    for (int i = tid; i < HD * (NN / 4); i += step) {
        int f = i / (NN / 4), c = i - f * (NN / 4);
        int n4 = c * 4;
        unsigned short* p = &xt[(long)f * NN + n4];
        uint2 u = *(uint2*)p, w;
        w.x = pk2(b2f_lo(u.x) * multg[n4], b2f_hi(u.x) * multg[n4 + 1]);
        w.y = pk2(b2f_lo(u.y) * multg[n4 + 2], b2f_hi(u.y) * multg[n4 + 3]);
        *(uint2*)p = w;
    }
}

// ---------------- fused layer v10 (champion): adjacency bulk-staged to LDS (aliased with sM),
//  x-tile transposed to sX in the PROLOGUE, k-loop = LDS adjacency + LUT decode +
//  depth-2 prefetched xT A-frags. Phase B pure-LDS operands. Grid (BGR, NTPB).
template<bool HASD, bool LAST>
__global__ __launch_bounds__(256, 3) void k_layer10(
    const unsigned short* __restrict__ xtin, unsigned short* __restrict__ xtout,
    const unsigned char* __restrict__ Amat,
    const float* __restrict__ alive, const float* __restrict__ rliv,
    const unsigned short* __restrict__ wr_bt, const unsigned short* __restrict__ ws_bt,
    const float* __restrict__ bias, float* __restrict__ hcat, int layer,
    const float* __restrict__ pwr, const float* __restrict__ pws, float* __restrict__ dd)
{
    // phase A: adjacency tile (80 x 208 B = 16.6 KB); phase B: sM mean tile (80 x 136 sh = 21.8 KB)
    __shared__ __align__(16) unsigned char sAM[NTPB * 16 * MSTR * 2];
    __shared__ __align__(16) unsigned short sX[NTPB * 16 * MSTR];   // x tile (node-major), 21.8 KB
    __shared__ unsigned int sLUT[256];                              // byte -> 2 packed bf16
    int g = blockIdx.x;
    int ntg = blockIdx.y;
    int t = threadIdx.x;
    long gbase = (long)g * NPG0;
    int lane = t & 63, wid = t >> 6;          // 4 waves
    int quad = lane >> 4, l15 = lane & 15;
    int mp = wid;                              // feature pair-group: m-tiles 2mp, 2mp+1
    int nbase = ntg * (NTPB * 16);             // local dst-node base
    int gi = t >> 2, j4 = t & 3;               // staging transpose group/lane

    sLUT[t] = pkb(bfint(t & 0xFu), bfint(t >> 4));

    // ---- prologue: issue adjacency bulk loads (1040 uint4) + x-tile loads, all in flight
    const unsigned char* Ag = Amat + (gbase + nbase) * (long)AST4;
    uint4 astg[5];
    {
        const uint4* Ag4 = (const uint4*)Ag;
#pragma unroll
        for (int r = 0; r < 5; ++r) {
            int c = t + r * 256;
            if (c < ACH4) astg[r] = Ag4[c];
        }
    }
    uint2 stg[10];
#pragma unroll
    for (int it = 0; it < 10; ++it) {
        int tid2 = gi + it * 64;
        int fg = tid2 / 20, ng = tid2 - fg * 20;
        stg[it] = *(const uint2*)&xtin[(long)(fg * 4 + j4) * NN + gbase + nbase + ng * 4];
    }
    float rl[NTPB];
#pragma unroll
    for (int nt = 0; nt < NTPB; ++nt) rl[nt] = rliv[gbase + nbase + nt * 16 + l15];

    // adjacency -> LDS (waits only on the adjacency loads)
#pragma unroll
    for (int r = 0; r < 5; ++r) {
        int c = t + r * 256;
        if (c < ACH4) *(uint4*)&sAM[c * 16] = astg[r];
    }
    // x-tile 4x4 shfl-transpose -> sX (node-major)
#pragma unroll
    for (int it = 0; it < 10; ++it) {
        int tid2 = gi + it * 64;
        int fg = tid2 / 20, ng = tid2 - fg * 20;
        uint2 u = stg[it];
        float a0 = b2f_lo(u.x), a1 = b2f_hi(u.x), a2 = b2f_lo(u.y), a3 = b2f_hi(u.y);
        float tw;
        bool bo1 = j4 & 1;
        tw = __shfl_xor(bo1 ? a0 : a1, 1); if (bo1) a0 = tw; else a1 = tw;
        tw = __shfl_xor(bo1 ? a2 : a3, 1); if (bo1) a2 = tw; else a3 = tw;
        bool bo2 = (j4 & 2) != 0;
        tw = __shfl_xor(bo2 ? a0 : a2, 2); if (bo2) a0 = tw; else a2 = tw;
        tw = __shfl_xor(bo2 ? a1 : a3, 2); if (bo2) a1 = tw; else a3 = tw;
        uint2 w; w.x = pk2(a0, a1); w.y = pk2(a2, a3);
        *(uint2*)&sX[(ng * 4 + j4) * MSTR + fg * 4] = w;
    }

    // prime depth-2 xT A-frag pipeline (global; issued before the barrier to drain under it)
    const unsigned short* xa0 = xtin + (long)(mp * 32 + l15) * NN + gbase;
    const unsigned short* xa1 = xa0 + (long)16 * NN;
    short8 Ac0 = *(const short8*)&xa0[quad * 8];
    short8 Ac1 = *(const short8*)&xa1[quad * 8];
    short8 An0 = *(const short8*)&xa0[32 + quad * 8];
    short8 An1 = *(const short8*)&xa1[32 + quad * 8];

    __syncthreads();   // sAM (adjacency) + sX + sLUT visible

    // ---- phase A: agg GEMM; adjacency from LDS + LUT, xT depth-2 prefetched
    floatx4 acc[NTPB][2];
#pragma unroll
    for (int nt = 0; nt < NTPB; ++nt) {
        acc[nt][0] = (floatx4){0.f, 0.f, 0.f, 0.f};
        acc[nt][1] = (floatx4){0.f, 0.f, 0.f, 0.f};
    }
    int abase = l15 * AST4 + quad * 4;
#pragma unroll
    for (int k = 0; k < KSA; ++k) {
        short8 Af0, Af1;
        if (k + 2 < KSA) {
            int ko = (k + 2) * 32 + quad * 8;
            Af0 = *(const short8*)&xa0[ko];
            Af1 = *(const short8*)&xa1[ko];
        }
#pragma unroll
        for (int nt = 0; nt < NTPB; ++nt) {
            unsigned int u = *(const unsigned int*)&sAM[abase + nt * (16 * AST4) + k * 16];
            short8 Bf = lutdec(u, sLUT);
            acc[nt][0] = __builtin_amdgcn_mfma_f32_16x16x32_bf16(Ac0, Bf, acc[nt][0], 0, 0, 0);
            acc[nt][1] = __builtin_amdgcn_mfma_f32_16x16x32_bf16(Ac1, Bf, acc[nt][1], 0, 0, 0);
        }
        if (k + 1 < KSA) { Ac0 = An0; Ac1 = An1; }
        if (k + 2 < KSA) { An0 = Af0; An1 = Af1; }
    }
    __syncthreads();   // all adjacency LDS reads done; sAM region becomes sM

    // ---- scale by rliv, write mean tile to sM (aliased region)
    unsigned short* sM = (unsigned short*)sAM;
#pragma unroll
    for (int nt = 0; nt < NTPB; ++nt) {
        int lo = nt * 16 + l15;
        unsigned short* mrow = &sM[lo * MSTR + 32 * mp + quad * 4];
        uint2 w0, w1;
        w0.x = pk2(acc[nt][0][0] * rl[nt], acc[nt][0][1] * rl[nt]);
        w0.y = pk2(acc[nt][0][2] * rl[nt], acc[nt][0][3] * rl[nt]);
        w1.x = pk2(acc[nt][1][0] * rl[nt], acc[nt][1][1] * rl[nt]);
        w1.y = pk2(acc[nt][1][2] * rl[nt], acc[nt][1][3] * rl[nt]);
        *(uint2*)mrow = w0;
        *(uint2*)(mrow + 16) = w1;
    }

    // ---- pre-barrier issue: W frags, bias, alive, pool weights
    short8 Wr8[2][4], Ws8[2][4];
#pragma unroll
    for (int mt = 0; mt < 2; ++mt) {
        int jj = (2 * mp + mt) * 16 + l15;
#pragma unroll
        for (int k = 0; k < 4; ++k) {
            Wr8[mt][k] = *(const short8*)&wr_bt[jj * HD + k * 32 + quad * 8];
            Ws8[mt][k] = *(const short8*)&ws_bt[jj * HD + k * 32 + quad * 8];
        }
    }
    float4 b40 = *(const float4*)&bias[(2 * mp) * 16 + quad * 4];
    float4 b41 = *(const float4*)&bias[(2 * mp + 1) * 16 + quad * 4];
    float av[NTPB];
#pragma unroll
    for (int nt = 0; nt < NTPB; ++nt) av[nt] = alive[gbase + nbase + nt * 16 + l15];

    float4 pwrA, pwrB, pwsA, pwsB;
    if (HASD) {
        pwrA = *(const float4*)&pwr[(2 * mp) * 16 + quad * 4];
        pwrB = *(const float4*)&pwr[(2 * mp + 1) * 16 + quad * 4];
        pwsA = *(const float4*)&pws[(2 * mp) * 16 + quad * 4];
        pwsB = *(const float4*)&pws[(2 * mp + 1) * 16 + quad * 4];
    }
    __syncthreads();   // sM visible

    // ---- phase B: transposed conv, pure LDS operands
    float ps0[4] = {0, 0, 0, 0}, ps1[4] = {0, 0, 0, 0};

#pragma unroll
    for (int nt = 0; nt < NTPB; ++nt) {
        int lo = nt * 16 + l15;
        long go = gbase + nbase + lo;
        floatx4 a0 = {b40.x, b40.y, b40.z, b40.w};
        floatx4 a1 = {b41.x, b41.y, b41.z, b41.w};
#pragma unroll
        for (int k = 0; k < 4; ++k) {
            short8 B0 = *(const short8*)&sM[lo * MSTR + k * 32 + quad * 8];
            a0 = __builtin_amdgcn_mfma_f32_16x16x32_bf16(Wr8[0][k], B0, a0, 0, 0, 0);
            a1 = __builtin_amdgcn_mfma_f32_16x16x32_bf16(Wr8[1][k], B0, a1, 0, 0, 0);
        }
#pragma unroll
        for (int k = 0; k < 4; ++k) {
            short8 B1 = *(const short8*)&sX[lo * MSTR + k * 32 + quad * 8];
            a0 = __builtin_amdgcn_mfma_f32_16x16x32_bf16(Ws8[0][k], B1, a0, 0, 0, 0);
            a1 = __builtin_amdgcn_mfma_f32_16x16x32_bf16(Ws8[1][k], B1, a1, 0, 0, 0);
        }
        bool liv = av[nt] != 0.0f;
        float v0r[4], v1r[4];
#pragma unroll
        for (int rr = 0; rr < 4; ++rr) {
            v0r[rr] = fmaxf(a0[rr], 0.0f);
            v1r[rr] = fmaxf(a1[rr], 0.0f);
            if (liv) { ps0[rr] += v0r[rr]; ps1[rr] += v1r[rr]; }
            if (!liv) { v0r[rr] = 0.0f; v1r[rr] = 0.0f; }
        }
        if (!LAST) {
            // feature-major store (acc layout is already OUT^T)
#pragma unroll
            for (int rr = 0; rr < 4; ++rr) {
                xtout[(long)(32 * mp + quad * 4 + rr) * NN + go] = f2b(v0r[rr]);
                xtout[(long)(32 * mp + 16 + quad * 4 + rr) * NN + go] = f2b(v1r[rr]);
            }
        }
        // pool-score partial dots (wave's 32 features), reduce over quads, store per-mp slot
        if (HASD) {
            float pr = v0r[0]*pwrA.x + v0r[1]*pwrA.y + v0r[2]*pwrA.z + v0r[3]*pwrA.w
                     + v1r[0]*pwrB.x + v1r[1]*pwrB.y + v1r[2]*pwrB.z + v1r[3]*pwrB.w;
            float pd = v0r[0]*pwsA.x + v0r[1]*pwsA.y + v0r[2]*pwsA.z + v0r[3]*pwsA.w
                     + v1r[0]*pwsB.x + v1r[1]*pwsB.y + v1r[2]*pwsB.z + v1r[3]*pwsB.w;
            pr += __shfl_xor(pr, 16); pr += __shfl_xor(pr, 32);
            pd += __shfl_xor(pd, 16); pd += __shfl_xor(pd, 32);
            if (quad == 0) {
                float2 st = {pr, pd};
                *(float2*)&dd[go * 8 + mp * 2] = st;
            }
        }
    }
    // fused readout: reduce over l15 (node lanes), atomic into hcat
#pragma unroll
    for (int rr = 0; rr < 4; ++rr) {
        float v = ps0[rr];
        v += __shfl_xor(v, 1); v += __shfl_xor(v, 2); v += __shfl_xor(v, 4); v += __shfl_xor(v, 8);
        float u = ps1[rr];
        u += __shfl_xor(u, 1); u += __shfl_xor(u, 2); u += __shfl_xor(u, 4); u += __shfl_xor(u, 8);
        if (l15 == 0) {
            atomicAdd(&hcat[g * (5 * HD) + layer * HD + (2 * mp) * 16 + quad * 4 + rr], v);
            atomicAdd(&hcat[g * (5 * HD) + layer * HD + (2 * mp + 1) * 16 + quad * 4 + rr], u);
        }
    }
}

// ---------------- pool v3 (512 thr): dense-adjacency neighbor sums; top-K; mult/alive/rliv
__global__ __launch_bounds__(512) void k_pool2(
    const float* __restrict__ dd, const unsigned int* __restrict__ A,
    float* __restrict__ multg, float* __restrict__ alive, float* __restrict__ rliv,
    const float* __restrict__ pb, int K)
{
    __shared__ float str[NPG0];
    __shared__ float stsb[NPG0];
    __shared__ float sal[NPG0];
    __shared__ float s[512];
    __shared__ float sc[NPG0];
    __shared__ float kf[NPG0];
    __shared__ unsigned char keep[NPG0];
    __shared__ int cnt_gt;
    int g = blockIdx.x, t = threadIdx.x;
    long nb = (long)g * NPG0;
    float pbv = pb[0];

    for (int n = t; n < NPG0; n += 512) {
        const float* dp = &dd[(nb + n) * 8];
        float4 da = *(const float4*)dp;
        float4 db = *(const float4*)(dp + 4);
        str[n] = da.x + da.z + db.x + db.z;          // x @ p_wr
        stsb[n] = da.y + da.w + db.y + db.w + pbv;   // x @ p_ws + b
        sal[n] = alive[nb + n];
    }
    if (t == 0) cnt_gt = 0;
    __syncthreads();

    for (int n = t; n < 512; n += 512) {
        float v = -INFINITY;
        if (n < NPG0 && sal[n] != 0.0f) {
            const uint4* Ar = (const uint4*)(A + ((long)g * NPG0 + n) * 52);
            float ssum = 0.0f;
#pragma unroll
            for (int c = 0; c < 13; ++c) {
                uint4 q = Ar[c];
                ssum += nibdot(q.x, &str[c * 32]);
                ssum += nibdot(q.y, &str[c * 32 + 8]);
                ssum += nibdot(q.z, &str[c * 32 + 16]);
                ssum += nibdot(q.w, &str[c * 32 + 24]);
            }
            v = ssum * rliv[nb + n] + stsb[n];
        }
        s[n] = v;
        if (n < NPG0) sc[n] = v;
    }
    __syncthreads();

    for (int ksz = 2; ksz <= 512; ksz <<= 1) {
        for (int jsz = ksz >> 1; jsz >= 1; jsz >>= 1) {
            for (int i = t; i < 512; i += 512) {
                int ixj = i ^ jsz;
                if (ixj > i) {
                    float a = s[i], c = s[ixj];
                    bool up = ((i & ksz) == 0);
                    if ((a > c) == up) { s[i] = c; s[ixj] = a; }
                }
            }
            __syncthreads();
        }
    }
    float thr = s[512 - K];
    for (int n = t; n < NPG0; n += 512)
        if (sc[n] > thr) atomicAdd(&cnt_gt, 1);
    __syncthreads();
    if (t == 0) {   // tie-break: lowest index (matches lax.top_k)
        int m = K - cnt_gt, tk = 0;
        for (int n = 0; n < NPG0; n++) {
            bool kp = sc[n] > thr;
            if (!kp && sc[n] == thr && tk < m) { kp = true; tk++; }
            keep[n] = kp ? 1 : 0;
        }
    }
    __syncthreads();
    for (int n = t; n < NPG0; n += 512) {
        multg[nb + n] = keep[n] ? tanhf(sc[n]) : 0.0f;
        alive[nb + n] = keep[n] ? 1.0f : 0.0f;
        kf[n] = keep[n] ? 1.0f : 0.0f;
    }
    __syncthreads();
    for (int n = t; n < NPG0; n += 512) {
        const uint4* Ar = (const uint4*)(A + ((long)g * NPG0 + n) * 52);
        float ssum = 0.0f;
#pragma unroll
        for (int c = 0; c < 13; ++c) {
            uint4 q = Ar[c];
            ssum += nibdot(q.x, &kf[c * 32]);
            ssum += nibdot(q.y, &kf[c * 32 + 8]);
            ssum += nibdot(q.z, &kf[c * 32 + 16]);
            ssum += nibdot(q.w, &kf[c * 32 + 24]);
        }
        rliv[nb + n] = 1.0f / fmaxf(ssum, 1.0f);
    }
}

// ---------------- final MLP + log_softmax (hcat holds SUMS; divide here)
__global__ __launch_bounds__(128) void k_mlp(const float* __restrict__ h, const float* __restrict__ w1,
    const float* __restrict__ b1, const float* __restrict__ w2,
    const float* __restrict__ b2, float* __restrict__ out) {
    __shared__ float h1[HD];
    __shared__ float red[HD];
    __shared__ float lg[2];
    const float inv[5] = {1.0f/400.0f, 1.0f/400.0f, 1.0f/320.0f, 1.0f/320.0f, 1.0f/256.0f};
    int g = blockIdx.x, j = threadIdx.x;
    const float* hg = &h[g * (5 * HD)];
    float acc = b1[j];
    for (int k = 0; k < 5 * HD; k++) acc += hg[k] * inv[k >> 7] * w1[k * HD + j];
    h1[j] = fmaxf(acc, 0.0f);
    __syncthreads();
    for (int c = 0; c < 2; c++) {
        red[j] = h1[j] * w2[j * 2 + c];
        __syncthreads();
        for (int st = 64; st > 0; st >>= 1) {
            if (j < st) red[j] += red[j + st];
            __syncthreads();
        }
        if (j == 0) lg[c] = red[0] + b2[c];
        __syncthreads();
    }
    if (j == 0) {
        float l0 = lg[0], l1 = lg[1];
        float m = fmaxf(l0, l1);
        float lse = m + logf(expf(l0 - m) + expf(l1 - m));
        out[g * 2 + 0] = l0 - lse;
        out[g * 2 + 1] = l1 - lse;
    }
}

extern "C" void kernel_launch(void* const* d_in, const int* in_sizes, int n_in,
                              void* d_out, int out_size, void* d_ws, size_t ws_size,
                              hipStream_t stream) {
    const float* x_in   = (const float*)d_in[0];
    const int*   eidx   = (const int*)d_in[1];
    const int*   e_src  = eidx;
    const int*   e_dst  = eidx + NE;
    const float* c1_wr  = (const float*)d_in[3];
    const float* c1_ws  = (const float*)d_in[4];
    const float* c1_b   = (const float*)d_in[5];
    const float* cs_wr  = (const float*)d_in[6];
    const float* cs_ws  = (const float*)d_in[7];
    const float* cs_b   = (const float*)d_in[8];
    const float* p_wr   = (const float*)d_in[9];
    const float* p_ws   = (const float*)d_in[10];
    const float* p_b    = (const float*)d_in[11];
    const float* l1_w   = (const float*)d_in[12];
    const float* l1_b   = (const float*)d_in[13];
    const float* l2_w   = (const float*)d_in[14];
    const float* l2_b   = (const float*)d_in[15];
    float* out = (float*)d_out;

    char* ws = (char*)d_ws;
    size_t off = 0;
    float* alive = (float*)(ws + off);           off += (size_t)NN * 4;
    float* rliv  = (float*)(ws + off);           off += (size_t)NN * 4;
    float* hcat  = (float*)(ws + off);           off += (size_t)BGR * 5 * HD * 4;
    unsigned short* wbt = (unsigned short*)(ws + off); off += (size_t)10 * HD * HD * 2;
    unsigned int* Amat = (unsigned int*)(ws + off);    off += (size_t)NN * 52 * 4;
    unsigned short* xtA = (unsigned short*)(ws + off); off += ((size_t)NN * HD + 32) * 2;
    unsigned short* xtB = (unsigned short*)(ws + off); off += ((size_t)NN * HD + 32) * 2;
    float* dd    = (float*)(ws + off);           off += (size_t)NN * 8 * 4;
    float* multg = (float*)(ws + off);           off += (size_t)NN * 4;

    hipMemsetAsync(hcat, 0, (size_t)BGR * 5 * HD * 4, stream);
    // zero the tails so the k=12 chunk of the last graph's last feature row reads zeros
    hipMemsetAsync(xtA + (size_t)NN * HD, 0, 64, stream);
    hipMemsetAsync(xtB + (size_t)NN * HD, 0, 64, stream);

    k_graph2<<<BGR, 512, 0, stream>>>(e_src, e_dst, Amat, alive, rliv);
    k_wcvt<<<dim3(64, 10), 256, 0, stream>>>(c1_wr, c1_ws, cs_wr, cs_ws, wbt);
    k_xt0<<<dim3(200, 32), 512, 0, stream>>>(x_in, xtB);

    unsigned short* bt_wr[5] = { wbt + 0 * HD * HD, wbt + 2 * HD * HD, wbt + 3 * HD * HD, wbt + 4 * HD * HD, wbt + 5 * HD * HD };
    unsigned short* bt_ws[5] = { wbt + 1 * HD * HD, wbt + 6 * HD * HD, wbt + 7 * HD * HD, wbt + 8 * HD * HD, wbt + 9 * HD * HD };
    const unsigned char* Am8 = (const unsigned char*)Amat;

    // L0 (conv1): xtB -> xtA
    k_layer10<false, false><<<dim3(BGR, NTPB), 256, 0, stream>>>(
        xtB, xtA, Am8, alive, rliv,
        bt_wr[0], bt_ws[0], c1_b, hcat, 0, nullptr, nullptr, nullptr);
    // L1 (convs[0]) + pool0 dots: xtA -> xtB
    k_layer10<true, false><<<dim3(BGR, NTPB), 256, 0, stream>>>(
        xtA, xtB, Am8, alive, rliv,
        bt_wr[1], bt_ws[1], cs_b + 0 * HD, hcat, 1, p_wr + 0 * HD, p_ws + 0 * HD, dd);
    // pool 0 (K=320)
    k_pool2<<<BGR, 512, 0, stream>>>(dd, Amat, multg, alive, rliv, p_b + 0, 320);
    k_scale<<<SCGRID, 256, 0, stream>>>(xtB, multg);
    // L2 (convs[1]): xtB -> xtA
    k_layer10<false, false><<<dim3(BGR, NTPB), 256, 0, stream>>>(
        xtB, xtA, Am8, alive, rliv,
        bt_wr[2], bt_ws[2], cs_b + 1 * HD, hcat, 2, nullptr, nullptr, nullptr);
    // L3 (convs[2]) + pool1 dots: xtA -> xtB
    k_layer10<true, false><<<dim3(BGR, NTPB), 256, 0, stream>>>(
        xtA, xtB, Am8, alive, rliv,
        bt_wr[3], bt_ws[3], cs_b + 2 * HD, hcat, 3, p_wr + 1 * HD, p_ws + 1 * HD, dd);
    // pool 1 (K=256)
    k_pool2<<<BGR, 512, 0, stream>>>(dd, Amat, multg, alive, rliv, p_b + 1, 256);
    k_scale<<<SCGRID, 256, 0, stream>>>(xtB, multg);
    // L4 (convs[3], no x output): xtB -> (readout only)
    k_layer10<false, true><<<dim3(BGR, NTPB), 256, 0, stream>>>(
        xtB, nullptr, Am8, alive, rliv,
        bt_wr[4], bt_ws[4], cs_b + 3 * HD, hcat, 4, nullptr, nullptr, nullptr);
    // MLP head
    k_mlp<<<BGR, HD, 0, stream>>>(hcat, l1_w, l1_b, l2_w, l2_b, out);
}

// Round 11
// 512.489 us; speedup vs baseline: 1.4203x; 1.0602x over previous
//
#include <hip/hip_runtime.h>
#include <math.h>

#define BGR 256        // graphs
#define NPG0 400       // nodes per graph
#define NN (BGR*NPG0)  // 102400 nodes
#define NE (NN*16)     // 1638400 edges
#define HD 128
#define AST4 208       // u4 adjacency row stride BYTES (416 nibbles = 13*32)
#define A32PG (NPG0*52) // u32 words per graph u4-adjacency slice = 20800
#define KSA 13         // agg k-steps (13*32 = 416)
#define MSTR 136       // LDS row stride (shorts), 16B-aligned
#define NTPB 5         // node-tiles (of 16) per block; 5 blocks cover a graph
#define SCGRID 2048    // wide-kernel grid
#define ACH4 1040      // adjacency tile uint4 chunks (80*208/16)

typedef __attribute__((ext_vector_type(8))) short short8;
typedef __attribute__((ext_vector_type(4))) float floatx4;
typedef __attribute__((ext_vector_type(4))) unsigned int uintx4;

__device__ __forceinline__ unsigned short f2b(float f) {
    unsigned int u = __builtin_bit_cast(unsigned int, f);
    unsigned int r = (u + 0x7fffu + ((u >> 16) & 1u)) >> 16;
    return (unsigned short)r;
}
__device__ __forceinline__ unsigned int pk2(float a, float b) {
    return (unsigned int)f2b(a) | ((unsigned int)f2b(b) << 16);
}
__device__ __forceinline__ float b2f_lo(unsigned int u) { return __builtin_bit_cast(float, u << 16); }
__device__ __forceinline__ float b2f_hi(unsigned int u) { return __builtin_bit_cast(float, u & 0xffff0000u); }
__device__ __forceinline__ short bfint(unsigned int v) {
    // exact bf16 of small nonneg int (v < 256)
    return (short)(__builtin_bit_cast(unsigned int, (float)v) >> 16);
}
__device__ __forceinline__ unsigned int pkb(short a, short b) {
    return (unsigned int)(unsigned short)a | ((unsigned int)(unsigned short)b << 16);
}
// u4 decode via LDS LUT: byte -> 2 packed bf16 (bit-identical to bfint path)
__device__ __forceinline__ short8 lutdec(unsigned int u, const unsigned int* lut) {
    uintx4 w;
    w[0] = lut[u & 0xFFu];
    w[1] = lut[(u >> 8) & 0xFFu];
    w[2] = lut[(u >> 16) & 0xFFu];
    w[3] = lut[u >> 24];
    return __builtin_bit_cast(short8, w);
}
// 8-nibble dot with an LDS float vector (broadcast reads)
__device__ __forceinline__ float nibdot(unsigned int u, const float* v) {
    return (float)(u & 0xFu) * v[0] + (float)((u >> 4) & 0xFu) * v[1]
         + (float)((u >> 8) & 0xFu) * v[2] + (float)((u >> 12) & 0xFu) * v[3]
         + (float)((u >> 16) & 0xFu) * v[4] + (float)((u >> 20) & 0xFu) * v[5]
         + (float)((u >> 24) & 0xFu) * v[6] + (float)(u >> 28) * v[7];
}

// ---------------- per-graph build: LDS-atomic u4 adjacency + alive/rliv (512 thr) ----------------
__global__ __launch_bounds__(512) void k_graph2(const int* __restrict__ src,
                                                const int* __restrict__ dst,
                                                unsigned int* __restrict__ A,
                                                float* __restrict__ alive,
                                                float* __restrict__ rliv) {
    __shared__ unsigned int sA[A32PG];   // 83.2 KB
    int g = blockIdx.x, t = threadIdx.x;
    {
        uint4 z = {0u, 0u, 0u, 0u};
        uint4* s4 = (uint4*)sA;
        for (int i = t; i < A32PG / 4; i += 512) s4[i] = z;
    }
    __syncthreads();
    int ebase = g * (NPG0 * 16);
    int gb = g * NPG0;
    for (int i = t; i < NPG0 * 16; i += 512) {
        int s = src[ebase + i] - gb;
        int d = dst[ebase + i] - gb;
        int nib = d * 416 + s;
        atomicAdd(&sA[nib >> 3], 1u << ((nib & 7) * 4));
    }
    __syncthreads();
    {
        uint4* Ao = (uint4*)(A + (long)g * A32PG);
        const uint4* si = (const uint4*)sA;
        for (int i = t; i < A32PG / 4; i += 512) Ao[i] = si[i];
    }
    for (int n = t; n < NPG0; n += 512) {
        const unsigned int* row = &sA[n * 52];
        unsigned int deg = 0;
        for (int c = 0; c < 52; ++c) {
            unsigned int u = row[c];
            unsigned int p = (u & 0x0F0F0F0Fu) + ((u >> 4) & 0x0F0F0F0Fu);
            deg += (p * 0x01010101u) >> 24;
        }
        alive[gb + n] = 1.0f;
        rliv[gb + n] = 1.0f / fmaxf((float)deg, 1.0f);
    }
}

// ---------------- W -> bf16, transposed: bt[m][j*128 + f] = bf16(W_m[f*128 + j]) = W^T row-major
__global__ void k_wcvt(const float* __restrict__ c1_wr, const float* __restrict__ c1_ws,
                       const float* __restrict__ cs_wr, const float* __restrict__ cs_ws,
                       unsigned short* __restrict__ bt) {
    int m = blockIdx.y;
    int idx = blockIdx.x * 256 + threadIdx.x;
    const float* W = (m == 0) ? c1_wr : (m == 1) ? c1_ws
                   : (m < 6) ? (cs_wr + (m - 2) * HD * HD) : (cs_ws + (m - 6) * HD * HD);
    int n = idx >> 7, k = idx & 127;
    bt[m * HD * HD + idx] = f2b(W[k * HD + n]);
}

// ---------------- one-time input transpose: x_in fp32 [NN][128] -> xT bf16 [128][NN]
__global__ __launch_bounds__(512) void k_xt0(const float* __restrict__ xin,
                                             unsigned short* __restrict__ xt) {
    int t = threadIdx.x;
    int ngrp = blockIdx.x * 128 + (t >> 2);   // node group (4 nodes)
    int j = t & 3;
    int r0 = ngrp * 4;
    int f0 = blockIdx.y * 4;                  // feature group (4 feats)
    float4 v = ((const float4*)xin)[(long)(r0 + j) * 32 + (f0 >> 2)];
    float a0 = v.x, a1 = v.y, a2 = v.z, a3 = v.w;
    float tw;
    bool bo1 = j & 1;
    tw = __shfl_xor(bo1 ? a0 : a1, 1); if (bo1) a0 = tw; else a1 = tw;
    tw = __shfl_xor(bo1 ? a2 : a3, 1); if (bo1) a2 = tw; else a3 = tw;
    bool bo2 = (j & 2) != 0;
    tw = __shfl_xor(bo2 ? a0 : a2, 2); if (bo2) a0 = tw; else a2 = tw;
    tw = __shfl_xor(bo2 ? a1 : a3, 2); if (bo2) a1 = tw; else a3 = tw;
    uint2 w; w.x = pk2(a0, a1); w.y = pk2(a2, a3);
    *(uint2*)&xt[(long)(f0 + j) * NN + r0] = w;
}

// ---------------- wide rescale: xT (feature-major) *= mult[node]
__global__ __launch_bounds__(256) void k_scale(unsigned short* __restrict__ xt,
                                               const float* __restrict__ multg)
{
    int tid = blockIdx.x * 256 + threadIdx.x;
    const int step = SCGRID * 256;
    for (int i = tid; i < HD * (NN / 4); i += step) {
        int f = i / (NN / 4), c = i - f * (NN / 4);
        int n4 = c * 4;
        unsigned short* p = &xt[(long)f * NN + n4];
        uint2 u = *(uint2*)p, w;
        w.x = pk2(b2f_lo(u.x) * multg[n4], b2f_hi(u.x) * multg[n4 + 1]);
        w.y = pk2(b2f_lo(u.y) * multg[n4 + 2], b2f_hi(u.y) * multg[n4 + 3]);
        *(uint2*)p = w;
    }
}

// ---------------- fused layer v10 (champion): adjacency bulk-staged to LDS (aliased with sM),
//  x-tile transposed to sX in the PROLOGUE, k-loop = LDS adjacency + LUT decode +
//  depth-2 prefetched xT A-frags. Phase B pure-LDS operands. Grid (BGR, NTPB).
template<bool HASD, bool LAST>
__global__ __launch_bounds__(256, 3) void k_layer10(
    const unsigned short* __restrict__ xtin, unsigned short* __restrict__ xtout,
    const unsigned char* __restrict__ Amat,
    const float* __restrict__ alive, const float* __restrict__ rliv,
    const unsigned short* __restrict__ wr_bt, const unsigned short* __restrict__ ws_bt,
    const float* __restrict__ bias, float* __restrict__ hcat, int layer,
    const float* __restrict__ pwr, const float* __restrict__ pws, float* __restrict__ dd)
{
    // phase A: adjacency tile (80 x 208 B = 16.6 KB); phase B: sM mean tile (80 x 136 sh = 21.8 KB)
    __shared__ __align__(16) unsigned char sAM[NTPB * 16 * MSTR * 2];
    __shared__ __align__(16) unsigned short sX[NTPB * 16 * MSTR];   // x tile (node-major), 21.8 KB
    __shared__ unsigned int sLUT[256];                              // byte -> 2 packed bf16
    int g = blockIdx.x;
    int ntg = blockIdx.y;
    int t = threadIdx.x;
    long gbase = (long)g * NPG0;
    int lane = t & 63, wid = t >> 6;          // 4 waves
    int quad = lane >> 4, l15 = lane & 15;
    int mp = wid;                              // feature pair-group: m-tiles 2mp, 2mp+1
    int nbase = ntg * (NTPB * 16);             // local dst-node base
    int gi = t >> 2, j4 = t & 3;               // staging transpose group/lane

    sLUT[t] = pkb(bfint(t & 0xFu), bfint(t >> 4));

    // ---- prologue: issue adjacency bulk loads (1040 uint4) + x-tile loads, all in flight
    const unsigned char* Ag = Amat + (gbase + nbase) * (long)AST4;
    uint4 astg[5];
    {
        const uint4* Ag4 = (const uint4*)Ag;
#pragma unroll
        for (int r = 0; r < 5; ++r) {
            int c = t + r * 256;
            if (c < ACH4) astg[r] = Ag4[c];
        }
    }
    uint2 stg[10];
#pragma unroll
    for (int it = 0; it < 10; ++it) {
        int tid2 = gi + it * 64;
        int fg = tid2 / 20, ng = tid2 - fg * 20;
        stg[it] = *(const uint2*)&xtin[(long)(fg * 4 + j4) * NN + gbase + nbase + ng * 4];
    }
    float rl[NTPB];
#pragma unroll
    for (int nt = 0; nt < NTPB; ++nt) rl[nt] = rliv[gbase + nbase + nt * 16 + l15];

    // adjacency -> LDS (waits only on the adjacency loads)
#pragma unroll
    for (int r = 0; r < 5; ++r) {
        int c = t + r * 256;
        if (c < ACH4) *(uint4*)&sAM[c * 16] = astg[r];
    }
    // x-tile 4x4 shfl-transpose -> sX (node-major)
#pragma unroll
    for (int it = 0; it < 10; ++it) {
        int tid2 = gi + it * 64;
        int fg = tid2 / 20, ng = tid2 - fg * 20;
        uint2 u = stg[it];
        float a0 = b2f_lo(u.x), a1 = b2f_hi(u.x), a2 = b2f_lo(u.y), a3 = b2f_hi(u.y);
        float tw;
        bool bo1 = j4 & 1;
        tw = __shfl_xor(bo1 ? a0 : a1, 1); if (bo1) a0 = tw; else a1 = tw;
        tw = __shfl_xor(bo1 ? a2 : a3, 1); if (bo1) a2 = tw; else a3 = tw;
        bool bo2 = (j4 & 2) != 0;
        tw = __shfl_xor(bo2 ? a0 : a2, 2); if (bo2) a0 = tw; else a2 = tw;
        tw = __shfl_xor(bo2 ? a1 : a3, 2); if (bo2) a1 = tw; else a3 = tw;
        uint2 w; w.x = pk2(a0, a1); w.y = pk2(a2, a3);
        *(uint2*)&sX[(ng * 4 + j4) * MSTR + fg * 4] = w;
    }

    // prime depth-2 xT A-frag pipeline (global; issued before the barrier to drain under it)
    const unsigned short* xa0 = xtin + (long)(mp * 32 + l15) * NN + gbase;
    const unsigned short* xa1 = xa0 + (long)16 * NN;
    short8 Ac0 = *(const short8*)&xa0[quad * 8];
    short8 Ac1 = *(const short8*)&xa1[quad * 8];
    short8 An0 = *(const short8*)&xa0[32 + quad * 8];
    short8 An1 = *(const short8*)&xa1[32 + quad * 8];

    __syncthreads();   // sAM (adjacency) + sX + sLUT visible

    // ---- phase A: agg GEMM; adjacency from LDS + LUT, xT depth-2 prefetched
    floatx4 acc[NTPB][2];
#pragma unroll
    for (int nt = 0; nt < NTPB; ++nt) {
        acc[nt][0] = (floatx4){0.f, 0.f, 0.f, 0.f};
        acc[nt][1] = (floatx4){0.f, 0.f, 0.f, 0.f};
    }
    int abase = l15 * AST4 + quad * 4;
#pragma unroll
    for (int k = 0; k < KSA; ++k) {
        short8 Af0, Af1;
        if (k + 2 < KSA) {
            int ko = (k + 2) * 32 + quad * 8;
            Af0 = *(const short8*)&xa0[ko];
            Af1 = *(const short8*)&xa1[ko];
        }
#pragma unroll
        for (int nt = 0; nt < NTPB; ++nt) {
            unsigned int u = *(const unsigned int*)&sAM[abase + nt * (16 * AST4) + k * 16];
            short8 Bf = lutdec(u, sLUT);
            acc[nt][0] = __builtin_amdgcn_mfma_f32_16x16x32_bf16(Ac0, Bf, acc[nt][0], 0, 0, 0);
            acc[nt][1] = __builtin_amdgcn_mfma_f32_16x16x32_bf16(Ac1, Bf, acc[nt][1], 0, 0, 0);
        }
        if (k + 1 < KSA) { Ac0 = An0; Ac1 = An1; }
        if (k + 2 < KSA) { An0 = Af0; An1 = Af1; }
    }
    __syncthreads();   // all adjacency LDS reads done; sAM region becomes sM

    // ---- scale by rliv, write mean tile to sM (aliased region)
    unsigned short* sM = (unsigned short*)sAM;
#pragma unroll
    for (int nt = 0; nt < NTPB; ++nt) {
        int lo = nt * 16 + l15;
        unsigned short* mrow = &sM[lo * MSTR + 32 * mp + quad * 4];
        uint2 w0, w1;
        w0.x = pk2(acc[nt][0][0] * rl[nt], acc[nt][0][1] * rl[nt]);
        w0.y = pk2(acc[nt][0][2] * rl[nt], acc[nt][0][3] * rl[nt]);
        w1.x = pk2(acc[nt][1][0] * rl[nt], acc[nt][1][1] * rl[nt]);
        w1.y = pk2(acc[nt][1][2] * rl[nt], acc[nt][1][3] * rl[nt]);
        *(uint2*)mrow = w0;
        *(uint2*)(mrow + 16) = w1;
    }

    // ---- pre-barrier issue: W frags, bias, alive, pool weights
    short8 Wr8[2][4], Ws8[2][4];
#pragma unroll
    for (int mt = 0; mt < 2; ++mt) {
        int jj = (2 * mp + mt) * 16 + l15;
#pragma unroll
        for (int k = 0; k < 4; ++k) {
            Wr8[mt][k] = *(const short8*)&wr_bt[jj * HD + k * 32 + quad * 8];
            Ws8[mt][k] = *(const short8*)&ws_bt[jj * HD + k * 32 + quad * 8];
        }
    }
    float4 b40 = *(const float4*)&bias[(2 * mp) * 16 + quad * 4];
    float4 b41 = *(const float4*)&bias[(2 * mp + 1) * 16 + quad * 4];
    float av[NTPB];
#pragma unroll
    for (int nt = 0; nt < NTPB; ++nt) av[nt] = alive[gbase + nbase + nt * 16 + l15];

    float4 pwrA, pwrB, pwsA, pwsB;
    if (HASD) {
        pwrA = *(const float4*)&pwr[(2 * mp) * 16 + quad * 4];
        pwrB = *(const float4*)&pwr[(2 * mp + 1) * 16 + quad * 4];
        pwsA = *(const float4*)&pws[(2 * mp) * 16 + quad * 4];
        pwsB = *(const float4*)&pws[(2 * mp + 1) * 16 + quad * 4];
    }
    __syncthreads();   // sM visible

    // ---- phase B: transposed conv, pure LDS operands
    float ps0[4] = {0, 0, 0, 0}, ps1[4] = {0, 0, 0, 0};

#pragma unroll
    for (int nt = 0; nt < NTPB; ++nt) {
        int lo = nt * 16 + l15;
        long go = gbase + nbase + lo;
        floatx4 a0 = {b40.x, b40.y, b40.z, b40.w};
        floatx4 a1 = {b41.x, b41.y, b41.z, b41.w};
#pragma unroll
        for (int k = 0; k < 4; ++k) {
            short8 B0 = *(const short8*)&sM[lo * MSTR + k * 32 + quad * 8];
            a0 = __builtin_amdgcn_mfma_f32_16x16x32_bf16(Wr8[0][k], B0, a0, 0, 0, 0);
            a1 = __builtin_amdgcn_mfma_f32_16x16x32_bf16(Wr8[1][k], B0, a1, 0, 0, 0);
        }
#pragma unroll
        for (int k = 0; k < 4; ++k) {
            short8 B1 = *(const short8*)&sX[lo * MSTR + k * 32 + quad * 8];
            a0 = __builtin_amdgcn_mfma_f32_16x16x32_bf16(Ws8[0][k], B1, a0, 0, 0, 0);
            a1 = __builtin_amdgcn_mfma_f32_16x16x32_bf16(Ws8[1][k], B1, a1, 0, 0, 0);
        }
        bool liv = av[nt] != 0.0f;
        float v0r[4], v1r[4];
#pragma unroll
        for (int rr = 0; rr < 4; ++rr) {
            v0r[rr] = fmaxf(a0[rr], 0.0f);
            v1r[rr] = fmaxf(a1[rr], 0.0f);
            if (liv) { ps0[rr] += v0r[rr]; ps1[rr] += v1r[rr]; }
            if (!liv) { v0r[rr] = 0.0f; v1r[rr] = 0.0f; }
        }
        if (!LAST) {
            // feature-major store (acc layout is already OUT^T)
#pragma unroll
            for (int rr = 0; rr < 4; ++rr) {
                xtout[(long)(32 * mp + quad * 4 + rr) * NN + go] = f2b(v0r[rr]);
                xtout[(long)(32 * mp + 16 + quad * 4 + rr) * NN + go] = f2b(v1r[rr]);
            }
        }
        // pool-score partial dots (wave's 32 features), reduce over quads, store per-mp slot
        if (HASD) {
            float pr = v0r[0]*pwrA.x + v0r[1]*pwrA.y + v0r[2]*pwrA.z + v0r[3]*pwrA.w
                     + v1r[0]*pwrB.x + v1r[1]*pwrB.y + v1r[2]*pwrB.z + v1r[3]*pwrB.w;
            float pd = v0r[0]*pwsA.x + v0r[1]*pwsA.y + v0r[2]*pwsA.z + v0r[3]*pwsA.w
                     + v1r[0]*pwsB.x + v1r[1]*pwsB.y + v1r[2]*pwsB.z + v1r[3]*pwsB.w;
            pr += __shfl_xor(pr, 16); pr += __shfl_xor(pr, 32);
            pd += __shfl_xor(pd, 16); pd += __shfl_xor(pd, 32);
            if (quad == 0) {
                float2 st = {pr, pd};
                *(float2*)&dd[go * 8 + mp * 2] = st;
            }
        }
    }
    // fused readout: reduce over l15 (node lanes), atomic into hcat
#pragma unroll
    for (int rr = 0; rr < 4; ++rr) {
        float v = ps0[rr];
        v += __shfl_xor(v, 1); v += __shfl_xor(v, 2); v += __shfl_xor(v, 4); v += __shfl_xor(v, 8);
        float u = ps1[rr];
        u += __shfl_xor(u, 1); u += __shfl_xor(u, 2); u += __shfl_xor(u, 4); u += __shfl_xor(u, 8);
        if (l15 == 0) {
            atomicAdd(&hcat[g * (5 * HD) + layer * HD + (2 * mp) * 16 + quad * 4 + rr], v);
            atomicAdd(&hcat[g * (5 * HD) + layer * HD + (2 * mp + 1) * 16 + quad * 4 + rr], u);
        }
    }
}

// ---------------- pool v4 (512 thr): dense-adjacency neighbor sums; top-K with
//  PARALLEL tie-break (bitmask + popcount prefix; identical semantics to the serial
//  lowest-index-first scan); mult/alive/rliv
__global__ __launch_bounds__(512) void k_pool2(
    const float* __restrict__ dd, const unsigned int* __restrict__ A,
    float* __restrict__ multg, float* __restrict__ alive, float* __restrict__ rliv,
    const float* __restrict__ pb, int K)
{
    __shared__ float str[NPG0];
    __shared__ float stsb[NPG0];
    __shared__ float sal[NPG0];
    __shared__ float s[512];
    __shared__ float sc[NPG0];
    __shared__ float kf[NPG0];
    __shared__ unsigned char keep[NPG0];
    __shared__ unsigned int tmsk[13];   // 416-bit tie mask
    __shared__ int cnt_gt;
    int g = blockIdx.x, t = threadIdx.x;
    long nb = (long)g * NPG0;
    float pbv = pb[0];

    for (int n = t; n < NPG0; n += 512) {
        const float* dp = &dd[(nb + n) * 8];
        float4 da = *(const float4*)dp;
        float4 db = *(const float4*)(dp + 4);
        str[n] = da.x + da.z + db.x + db.z;          // x @ p_wr
        stsb[n] = da.y + da.w + db.y + db.w + pbv;   // x @ p_ws + b
        sal[n] = alive[nb + n];
    }
    if (t == 0) cnt_gt = 0;
    if (t < 13) tmsk[t] = 0u;
    __syncthreads();

    for (int n = t; n < 512; n += 512) {
        float v = -INFINITY;
        if (n < NPG0 && sal[n] != 0.0f) {
            const uint4* Ar = (const uint4*)(A + ((long)g * NPG0 + n) * 52);
            float ssum = 0.0f;
#pragma unroll
            for (int c = 0; c < 13; ++c) {
                uint4 q = Ar[c];
                ssum += nibdot(q.x, &str[c * 32]);
                ssum += nibdot(q.y, &str[c * 32 + 8]);
                ssum += nibdot(q.z, &str[c * 32 + 16]);
                ssum += nibdot(q.w, &str[c * 32 + 24]);
            }
            v = ssum * rliv[nb + n] + stsb[n];
        }
        s[n] = v;
        if (n < NPG0) sc[n] = v;
    }
    __syncthreads();

    for (int ksz = 2; ksz <= 512; ksz <<= 1) {
        for (int jsz = ksz >> 1; jsz >= 1; jsz >>= 1) {
            for (int i = t; i < 512; i += 512) {
                int ixj = i ^ jsz;
                if (ixj > i) {
                    float a = s[i], c = s[ixj];
                    bool up = ((i & ksz) == 0);
                    if ((a > c) == up) { s[i] = c; s[ixj] = a; }
                }
            }
            __syncthreads();
        }
    }
    float thr = s[512 - K];
    // count strict-greater and record ties in the bitmask (one pass)
    for (int n = t; n < NPG0; n += 512) {
        if (sc[n] > thr) atomicAdd(&cnt_gt, 1);
        else if (sc[n] == thr) atomicOr(&tmsk[n >> 5], 1u << (n & 31));
    }
    __syncthreads();
    int m = K - cnt_gt;
    // parallel tie-break: accept ties with rank (by index) < m — identical to serial scan
    for (int n = t; n < NPG0; n += 512) {
        bool kp = sc[n] > thr;
        if (!kp && sc[n] == thr) {
            int w = n >> 5;
            int rank = __popc(tmsk[w] & ((1u << (n & 31)) - 1u));
            for (int j = 0; j < w; ++j) rank += __popc(tmsk[j]);
            kp = rank < m;
        }
        keep[n] = kp ? 1 : 0;
    }
    __syncthreads();
    for (int n = t; n < NPG0; n += 512) {
        multg[nb + n] = keep[n] ? tanhf(sc[n]) : 0.0f;
        alive[nb + n] = keep[n] ? 1.0f : 0.0f;
        kf[n] = keep[n] ? 1.0f : 0.0f;
    }
    __syncthreads();
    for (int n = t; n < NPG0; n += 512) {
        const uint4* Ar = (const uint4*)(A + ((long)g * NPG0 + n) * 52);
        float ssum = 0.0f;
#pragma unroll
        for (int c = 0; c < 13; ++c) {
            uint4 q = Ar[c];
            ssum += nibdot(q.x, &kf[c * 32]);
            ssum += nibdot(q.y, &kf[c * 32 + 8]);
            ssum += nibdot(q.z, &kf[c * 32 + 16]);
            ssum += nibdot(q.w, &kf[c * 32 + 24]);
        }
        rliv[nb + n] = 1.0f / fmaxf(ssum, 1.0f);
    }
}

// ---------------- final MLP + log_softmax (hcat holds SUMS; divide here)
__global__ __launch_bounds__(128) void k_mlp(const float* __restrict__ h, const float* __restrict__ w1,
    const float* __restrict__ b1, const float* __restrict__ w2,
    const float* __restrict__ b2, float* __restrict__ out) {
    __shared__ float h1[HD];
    __shared__ float red[HD];
    __shared__ float lg[2];
    const float inv[5] = {1.0f/400.0f, 1.0f/400.0f, 1.0f/320.0f, 1.0f/320.0f, 1.0f/256.0f};
    int g = blockIdx.x, j = threadIdx.x;
    const float* hg = &h[g * (5 * HD)];
    float acc = b1[j];
    for (int k = 0; k < 5 * HD; k++) acc += hg[k] * inv[k >> 7] * w1[k * HD + j];
    h1[j] = fmaxf(acc, 0.0f);
    __syncthreads();
    for (int c = 0; c < 2; c++) {
        red[j] = h1[j] * w2[j * 2 + c];
        __syncthreads();
        for (int st = 64; st > 0; st >>= 1) {
            if (j < st) red[j] += red[j + st];
            __syncthreads();
        }
        if (j == 0) lg[c] = red[0] + b2[c];
        __syncthreads();
    }
    if (j == 0) {
        float l0 = lg[0], l1 = lg[1];
        float m = fmaxf(l0, l1);
        float lse = m + logf(expf(l0 - m) + expf(l1 - m));
        out[g * 2 + 0] = l0 - lse;
        out[g * 2 + 1] = l1 - lse;
    }
}

extern "C" void kernel_launch(void* const* d_in, const int* in_sizes, int n_in,
                              void* d_out, int out_size, void* d_ws, size_t ws_size,
                              hipStream_t stream) {
    const float* x_in   = (const float*)d_in[0];
    const int*   eidx   = (const int*)d_in[1];
    const int*   e_src  = eidx;
    const int*   e_dst  = eidx + NE;
    const float* c1_wr  = (const float*)d_in[3];
    const float* c1_ws  = (const float*)d_in[4];
    const float* c1_b   = (const float*)d_in[5];
    const float* cs_wr  = (const float*)d_in[6];
    const float* cs_ws  = (const float*)d_in[7];
    const float* cs_b   = (const float*)d_in[8];
    const float* p_wr   = (const float*)d_in[9];
    const float* p_ws   = (const float*)d_in[10];
    const float* p_b    = (const float*)d_in[11];
    const float* l1_w   = (const float*)d_in[12];
    const float* l1_b   = (const float*)d_in[13];
    const float* l2_w   = (const float*)d_in[14];
    const float* l2_b   = (const float*)d_in[15];
    float* out = (float*)d_out;

    char* ws = (char*)d_ws;
    size_t off = 0;
    float* alive = (float*)(ws + off);           off += (size_t)NN * 4;
    float* rliv  = (float*)(ws + off);           off += (size_t)NN * 4;
    float* hcat  = (float*)(ws + off);           off += (size_t)BGR * 5 * HD * 4;
    unsigned short* wbt = (unsigned short*)(ws + off); off += (size_t)10 * HD * HD * 2;
    unsigned int* Amat = (unsigned int*)(ws + off);    off += (size_t)NN * 52 * 4;
    unsigned short* xtA = (unsigned short*)(ws + off); off += ((size_t)NN * HD + 32) * 2;
    unsigned short* xtB = (unsigned short*)(ws + off); off += ((size_t)NN * HD + 32) * 2;
    float* dd    = (float*)(ws + off);           off += (size_t)NN * 8 * 4;
    float* multg = (float*)(ws + off);           off += (size_t)NN * 4;

    hipMemsetAsync(hcat, 0, (size_t)BGR * 5 * HD * 4, stream);
    // zero the tails so the k=12 chunk of the last graph's last feature row reads zeros
    hipMemsetAsync(xtA + (size_t)NN * HD, 0, 64, stream);
    hipMemsetAsync(xtB + (size_t)NN * HD, 0, 64, stream);

    k_graph2<<<BGR, 512, 0, stream>>>(e_src, e_dst, Amat, alive, rliv);
    k_wcvt<<<dim3(64, 10), 256, 0, stream>>>(c1_wr, c1_ws, cs_wr, cs_ws, wbt);
    k_xt0<<<dim3(200, 32), 512, 0, stream>>>(x_in, xtB);

    unsigned short* bt_wr[5] = { wbt + 0 * HD * HD, wbt + 2 * HD * HD, wbt + 3 * HD * HD, wbt + 4 * HD * HD, wbt + 5 * HD * HD };
    unsigned short* bt_ws[5] = { wbt + 1 * HD * HD, wbt + 6 * HD * HD, wbt + 7 * HD * HD, wbt + 8 * HD * HD, wbt + 9 * HD * HD };
    const unsigned char* Am8 = (const unsigned char*)Amat;

    // L0 (conv1): xtB -> xtA
    k_layer10<false, false><<<dim3(BGR, NTPB), 256, 0, stream>>>(
        xtB, xtA, Am8, alive, rliv,
        bt_wr[0], bt_ws[0], c1_b, hcat, 0, nullptr, nullptr, nullptr);
    // L1 (convs[0]) + pool0 dots: xtA -> xtB
    k_layer10<true, false><<<dim3(BGR, NTPB), 256, 0, stream>>>(
        xtA, xtB, Am8, alive, rliv,
        bt_wr[1], bt_ws[1], cs_b + 0 * HD, hcat, 1, p_wr + 0 * HD, p_ws + 0 * HD, dd);
    // pool 0 (K=320)
    k_pool2<<<BGR, 512, 0, stream>>>(dd, Amat, multg, alive, rliv, p_b + 0, 320);
    k_scale<<<SCGRID, 256, 0, stream>>>(xtB, multg);
    // L2 (convs[1]): xtB -> xtA
    k_layer10<false, false><<<dim3(BGR, NTPB), 256, 0, stream>>>(
        xtB, xtA, Am8, alive, rliv,
        bt_wr[2], bt_ws[2], cs_b + 1 * HD, hcat, 2, nullptr, nullptr, nullptr);
    // L3 (convs[2]) + pool1 dots: xtA -> xtB
    k_layer10<true, false><<<dim3(BGR, NTPB), 256, 0, stream>>>(
        xtA, xtB, Am8, alive, rliv,
        bt_wr[3], bt_ws[3], cs_b + 2 * HD, hcat, 3, p_wr + 1 * HD, p_ws + 1 * HD, dd);
    // pool 1 (K=256)
    k_pool2<<<BGR, 512, 0, stream>>>(dd, Amat, multg, alive, rliv, p_b + 1, 256);
    k_scale<<<SCGRID, 256, 0, stream>>>(xtB, multg);
    // L4 (convs[3], no x output): xtB -> (readout only)
    k_layer10<false, true><<<dim3(BGR, NTPB), 256, 0, stream>>>(
        xtB, nullptr, Am8, alive, rliv,
        bt_wr[4], bt_ws[4], cs_b + 3 * HD, hcat, 4, nullptr, nullptr, nullptr);
    // MLP head
    k_mlp<<<BGR, HD, 0, stream>>>(hcat, l1_w, l1_b, l2_w, l2_b, out);
}

// Round 12
// 467.003 us; speedup vs baseline: 1.5586x; 1.0974x over previous
//
#include <hip/hip_runtime.h>
#include <math.h>

#define BGR 256        // graphs
#define NPG0 400       // nodes per graph
#define NN (BGR*NPG0)  // 102400 nodes
#define NE (NN*16)     // 1638400 edges
#define HD 128
#define AST4 208       // u4 adjacency row stride BYTES (416 nibbles = 13*32)
#define A32PG (NPG0*52) // u32 words per graph u4-adjacency slice = 20800
#define KSA 13         // agg k-steps (13*32 = 416)
#define MSTR 136       // LDS row stride (shorts), 16B-aligned
#define NTPB 5         // node-tiles (of 16) per block; 5 blocks cover a graph
#define SCGRID 2048    // wide-kernel grid
#define ACH4 1040      // adjacency tile uint4 chunks (80*208/16)
#define TPG 25         // 16-node tiles per graph
#define TSTR 2048      // shorts per tile (128 feats x 16 nodes)
#define GSTR (TPG*TSTR) // shorts per graph in tiled-xT = 51200

typedef __attribute__((ext_vector_type(8))) short short8;
typedef __attribute__((ext_vector_type(4))) float floatx4;
typedef __attribute__((ext_vector_type(4))) unsigned int uintx4;

__device__ __forceinline__ unsigned short f2b(float f) {
    unsigned int u = __builtin_bit_cast(unsigned int, f);
    unsigned int r = (u + 0x7fffu + ((u >> 16) & 1u)) >> 16;
    return (unsigned short)r;
}
__device__ __forceinline__ unsigned int pk2(float a, float b) {
    return (unsigned int)f2b(a) | ((unsigned int)f2b(b) << 16);
}
__device__ __forceinline__ float b2f_lo(unsigned int u) { return __builtin_bit_cast(float, u << 16); }
__device__ __forceinline__ float b2f_hi(unsigned int u) { return __builtin_bit_cast(float, u & 0xffff0000u); }
__device__ __forceinline__ short bfint(unsigned int v) {
    // exact bf16 of small nonneg int (v < 256)
    return (short)(__builtin_bit_cast(unsigned int, (float)v) >> 16);
}
__device__ __forceinline__ unsigned int pkb(short a, short b) {
    return (unsigned int)(unsigned short)a | ((unsigned int)(unsigned short)b << 16);
}
// u4 decode via LDS LUT: byte -> 2 packed bf16 (bit-identical to bfint path)
__device__ __forceinline__ short8 lutdec(unsigned int u, const unsigned int* lut) {
    uintx4 w;
    w[0] = lut[u & 0xFFu];
    w[1] = lut[(u >> 8) & 0xFFu];
    w[2] = lut[(u >> 16) & 0xFFu];
    w[3] = lut[u >> 24];
    return __builtin_bit_cast(short8, w);
}
// 8-nibble dot with an LDS float vector (broadcast reads)
__device__ __forceinline__ float nibdot(unsigned int u, const float* v) {
    return (float)(u & 0xFu) * v[0] + (float)((u >> 4) & 0xFu) * v[1]
         + (float)((u >> 8) & 0xFu) * v[2] + (float)((u >> 12) & 0xFu) * v[3]
         + (float)((u >> 16) & 0xFu) * v[4] + (float)((u >> 20) & 0xFu) * v[5]
         + (float)((u >> 24) & 0xFu) * v[6] + (float)(u >> 28) * v[7];
}

// ---------------- per-graph build: LDS-atomic u4 adjacency + alive/rliv (512 thr) ----------------
__global__ __launch_bounds__(512) void k_graph2(const int* __restrict__ src,
                                                const int* __restrict__ dst,
                                                unsigned int* __restrict__ A,
                                                float* __restrict__ alive,
                                                float* __restrict__ rliv) {
    __shared__ unsigned int sA[A32PG];   // 83.2 KB
    int g = blockIdx.x, t = threadIdx.x;
    {
        uint4 z = {0u, 0u, 0u, 0u};
        uint4* s4 = (uint4*)sA;
        for (int i = t; i < A32PG / 4; i += 512) s4[i] = z;
    }
    __syncthreads();
    int ebase = g * (NPG0 * 16);
    int gb = g * NPG0;
    for (int i = t; i < NPG0 * 16; i += 512) {
        int s = src[ebase + i] - gb;
        int d = dst[ebase + i] - gb;
        int nib = d * 416 + s;
        atomicAdd(&sA[nib >> 3], 1u << ((nib & 7) * 4));
    }
    __syncthreads();
    {
        uint4* Ao = (uint4*)(A + (long)g * A32PG);
        const uint4* si = (const uint4*)sA;
        for (int i = t; i < A32PG / 4; i += 512) Ao[i] = si[i];
    }
    for (int n = t; n < NPG0; n += 512) {
        const unsigned int* row = &sA[n * 52];
        unsigned int deg = 0;
        for (int c = 0; c < 52; ++c) {
            unsigned int u = row[c];
            unsigned int p = (u & 0x0F0F0F0Fu) + ((u >> 4) & 0x0F0F0F0Fu);
            deg += (p * 0x01010101u) >> 24;
        }
        alive[gb + n] = 1.0f;
        rliv[gb + n] = 1.0f / fmaxf((float)deg, 1.0f);
    }
}

// ---------------- W -> bf16, transposed: bt[m][j*128 + f] = bf16(W_m[f*128 + j]) = W^T row-major
__global__ void k_wcvt(const float* __restrict__ c1_wr, const float* __restrict__ c1_ws,
                       const float* __restrict__ cs_wr, const float* __restrict__ cs_ws,
                       unsigned short* __restrict__ bt) {
    int m = blockIdx.y;
    int idx = blockIdx.x * 256 + threadIdx.x;
    const float* W = (m == 0) ? c1_wr : (m == 1) ? c1_ws
                   : (m < 6) ? (cs_wr + (m - 2) * HD * HD) : (cs_ws + (m - 6) * HD * HD);
    int n = idx >> 7, k = idx & 127;
    bt[m * HD * HD + idx] = f2b(W[k * HD + n]);
}

// ---------------- one-time input transpose: x_in fp32 [NN][128] -> tiled xT [g*25+tl][f][16]
__global__ __launch_bounds__(512) void k_xt0(const float* __restrict__ xin,
                                             unsigned short* __restrict__ xt) {
    int t = threadIdx.x;
    int ngrp = blockIdx.x * 128 + (t >> 2);   // node group (4 nodes)
    int j = t & 3;
    int r0 = ngrp * 4;
    int f0 = blockIdx.y * 4;                  // feature group (4 feats)
    float4 v = ((const float4*)xin)[(long)(r0 + j) * 32 + (f0 >> 2)];
    float a0 = v.x, a1 = v.y, a2 = v.z, a3 = v.w;
    float tw;
    bool bo1 = j & 1;
    tw = __shfl_xor(bo1 ? a0 : a1, 1); if (bo1) a0 = tw; else a1 = tw;
    tw = __shfl_xor(bo1 ? a2 : a3, 1); if (bo1) a2 = tw; else a3 = tw;
    bool bo2 = (j & 2) != 0;
    tw = __shfl_xor(bo2 ? a0 : a2, 2); if (bo2) a0 = tw; else a2 = tw;
    tw = __shfl_xor(bo2 ? a1 : a3, 2); if (bo2) a1 = tw; else a3 = tw;
    uint2 w; w.x = pk2(a0, a1); w.y = pk2(a2, a3);
    int g = r0 / NPG0;
    int ln = r0 - g * NPG0;
    int tl = ln >> 4, n0 = ln & 15;
    *(uint2*)&xt[((long)(g * TPG + tl) * HD + f0 + j) * 16 + n0] = w;
}

// ---------------- wide rescale: tiled xT *= mult[node]
__global__ __launch_bounds__(256) void k_scale(unsigned short* __restrict__ xt,
                                               const float* __restrict__ multg)
{
    int tid = blockIdx.x * 256 + threadIdx.x;
    const int step = SCGRID * 256;
    const int total = BGR * TPG * 512;        // uint2 chunks (512 per tile)
    for (int i = tid; i < total; i += step) {
        int gt = i >> 9;                       // tile id
        int rem = i & 511;
        int f = rem >> 2;
        int n0 = (rem & 3) * 4;
        int g = gt / TPG, tl = gt - g * TPG;
        int nb = g * NPG0 + tl * 16 + n0;
        unsigned short* p = &xt[(long)gt * TSTR + f * 16 + n0];
        uint2 u = *(uint2*)p, w;
        w.x = pk2(b2f_lo(u.x) * multg[nb], b2f_hi(u.x) * multg[nb + 1]);
        w.y = pk2(b2f_lo(u.y) * multg[nb + 2], b2f_hi(u.y) * multg[nb + 3]);
        *(uint2*)p = w;
    }
}

// ---------------- fused layer v14: tiled-xT layout; adjacency LDS-staged (aliased with sM),
//  prologue sX transpose (contiguous tile reads), k-loop = LDS adjacency + LUT decode +
//  depth-2 tiled-xT A-frag prefetch. Phase B pure-LDS operands; full-line tiled stores.
template<bool HASD, bool LAST>
__global__ __launch_bounds__(256, 3) void k_layer14(
    const unsigned short* __restrict__ xtin, unsigned short* __restrict__ xtout,
    const unsigned char* __restrict__ Amat,
    const float* __restrict__ alive, const float* __restrict__ rliv,
    const unsigned short* __restrict__ wr_bt, const unsigned short* __restrict__ ws_bt,
    const float* __restrict__ bias, float* __restrict__ hcat, int layer,
    const float* __restrict__ pwr, const float* __restrict__ pws, float* __restrict__ dd)
{
    // phase A: adjacency tile (80 x 208 B = 16.6 KB); phase B: sM mean tile (80 x 136 sh = 21.8 KB)
    __shared__ __align__(16) unsigned char sAM[NTPB * 16 * MSTR * 2];
    __shared__ __align__(16) unsigned short sX[NTPB * 16 * MSTR];   // x tile (node-major), 21.8 KB
    __shared__ unsigned int sLUT[256];                              // byte -> 2 packed bf16
    int g = blockIdx.x;
    int ntg = blockIdx.y;
    int t = threadIdx.x;
    long gbase = (long)g * NPG0;
    int lane = t & 63, wid = t >> 6;          // 4 waves
    int quad = lane >> 4, l15 = lane & 15;
    int mp = wid;                              // feature pair-group: m-tiles 2mp, 2mp+1
    int nbase = ntg * (NTPB * 16);             // local dst-node base
    int gi = t >> 2, j4 = t & 3;               // staging transpose group/lane

    sLUT[t] = pkb(bfint(t & 0xFu), bfint(t >> 4));

    // ---- prologue: issue adjacency bulk loads (1040 uint4) + x-tile loads, all in flight
    const unsigned char* Ag = Amat + (gbase + nbase) * (long)AST4;
    uint4 astg[5];
    {
        const uint4* Ag4 = (const uint4*)Ag;
#pragma unroll
        for (int r = 0; r < 5; ++r) {
            int c = t + r * 256;
            if (c < ACH4) astg[r] = Ag4[c];
        }
    }
    long gt0 = (long)(g * TPG + ntg * NTPB);   // block's first tile id
    uint2 stg[10];
#pragma unroll
    for (int it = 0; it < 10; ++it) {
        int tid2 = gi + it * 64;
        int tl = tid2 >> 7;                    // 0..4
        int rem = tid2 & 127;
        int fg = rem >> 2;                     // 0..31
        int ng = rem & 3;                      // 0..3
        stg[it] = *(const uint2*)&xtin[((gt0 + tl) * HD + fg * 4 + j4) * 16 + ng * 4];
    }
    float rl[NTPB];
#pragma unroll
    for (int nt = 0; nt < NTPB; ++nt) rl[nt] = rliv[gbase + nbase + nt * 16 + l15];

    // adjacency -> LDS (waits only on the adjacency loads)
#pragma unroll
    for (int r = 0; r < 5; ++r) {
        int c = t + r * 256;
        if (c < ACH4) *(uint4*)&sAM[c * 16] = astg[r];
    }
    // x-tile 4x4 shfl-transpose -> sX (node-major)
#pragma unroll
    for (int it = 0; it < 10; ++it) {
        int tid2 = gi + it * 64;
        int tl = tid2 >> 7;
        int rem = tid2 & 127;
        int fg = rem >> 2;
        int ng = rem & 3;
        uint2 u = stg[it];
        float a0 = b2f_lo(u.x), a1 = b2f_hi(u.x), a2 = b2f_lo(u.y), a3 = b2f_hi(u.y);
        float tw;
        bool bo1 = j4 & 1;
        tw = __shfl_xor(bo1 ? a0 : a1, 1); if (bo1) a0 = tw; else a1 = tw;
        tw = __shfl_xor(bo1 ? a2 : a3, 1); if (bo1) a2 = tw; else a3 = tw;
        bool bo2 = (j4 & 2) != 0;
        tw = __shfl_xor(bo2 ? a0 : a2, 2); if (bo2) a0 = tw; else a2 = tw;
        tw = __shfl_xor(bo2 ? a1 : a3, 2); if (bo2) a1 = tw; else a3 = tw;
        uint2 w; w.x = pk2(a0, a1); w.y = pk2(a2, a3);
        *(uint2*)&sX[(tl * 16 + ng * 4 + j4) * MSTR + fg * 4] = w;
    }

    // prime depth-2 xT A-frag pipeline (tiled layout: stride 2*TSTR shorts per k)
    const unsigned short* Xg = xtin + (long)g * GSTR;
    int qhi = quad >> 1, qlo = (quad & 1) * 8;
    const unsigned short* xb0 = Xg + (long)qhi * TSTR + (mp * 32 + l15) * 16 + qlo;
    const unsigned short* xb1 = xb0 + 16 * 16;   // +16 features
    short8 Ac0 = *(const short8*)&xb0[0];
    short8 Ac1 = *(const short8*)&xb1[0];
    short8 An0 = *(const short8*)&xb0[2 * TSTR];
    short8 An1 = *(const short8*)&xb1[2 * TSTR];

    __syncthreads();   // sAM (adjacency) + sX + sLUT visible

    // ---- phase A: agg GEMM; adjacency from LDS + LUT, xT depth-2 prefetched
    floatx4 acc[NTPB][2];
#pragma unroll
    for (int nt = 0; nt < NTPB; ++nt) {
        acc[nt][0] = (floatx4){0.f, 0.f, 0.f, 0.f};
        acc[nt][1] = (floatx4){0.f, 0.f, 0.f, 0.f};
    }
    int abase = l15 * AST4 + quad * 4;
#pragma unroll
    for (int k = 0; k < KSA; ++k) {
        short8 Af0, Af1;
        if (k + 2 < KSA) {
            Af0 = *(const short8*)&xb0[(k + 2) * 2 * TSTR];
            Af1 = *(const short8*)&xb1[(k + 2) * 2 * TSTR];
        }
#pragma unroll
        for (int nt = 0; nt < NTPB; ++nt) {
            unsigned int u = *(const unsigned int*)&sAM[abase + nt * (16 * AST4) + k * 16];
            short8 Bf = lutdec(u, sLUT);
            acc[nt][0] = __builtin_amdgcn_mfma_f32_16x16x32_bf16(Ac0, Bf, acc[nt][0], 0, 0, 0);
            acc[nt][1] = __builtin_amdgcn_mfma_f32_16x16x32_bf16(Ac1, Bf, acc[nt][1], 0, 0, 0);
        }
        if (k + 1 < KSA) { Ac0 = An0; Ac1 = An1; }
        if (k + 2 < KSA) { An0 = Af0; An1 = Af1; }
    }
    __syncthreads();   // all adjacency LDS reads done; sAM region becomes sM

    // ---- scale by rliv, write mean tile to sM (aliased region)
    unsigned short* sM = (unsigned short*)sAM;
#pragma unroll
    for (int nt = 0; nt < NTPB; ++nt) {
        int lo = nt * 16 + l15;
        unsigned short* mrow = &sM[lo * MSTR + 32 * mp + quad * 4];
        uint2 w0, w1;
        w0.x = pk2(acc[nt][0][0] * rl[nt], acc[nt][0][1] * rl[nt]);
        w0.y = pk2(acc[nt][0][2] * rl[nt], acc[nt][0][3] * rl[nt]);
        w1.x = pk2(acc[nt][1][0] * rl[nt], acc[nt][1][1] * rl[nt]);
        w1.y = pk2(acc[nt][1][2] * rl[nt], acc[nt][1][3] * rl[nt]);
        *(uint2*)mrow = w0;
        *(uint2*)(mrow + 16) = w1;
    }

    // ---- pre-barrier issue: W frags, bias, alive, pool weights
    short8 Wr8[2][4], Ws8[2][4];
#pragma unroll
    for (int mt = 0; mt < 2; ++mt) {
        int jj = (2 * mp + mt) * 16 + l15;
#pragma unroll
        for (int k = 0; k < 4; ++k) {
            Wr8[mt][k] = *(const short8*)&wr_bt[jj * HD + k * 32 + quad * 8];
            Ws8[mt][k] = *(const short8*)&ws_bt[jj * HD + k * 32 + quad * 8];
        }
    }
    float4 b40 = *(const float4*)&bias[(2 * mp) * 16 + quad * 4];
    float4 b41 = *(const float4*)&bias[(2 * mp + 1) * 16 + quad * 4];
    float av[NTPB];
#pragma unroll
    for (int nt = 0; nt < NTPB; ++nt) av[nt] = alive[gbase + nbase + nt * 16 + l15];

    float4 pwrA, pwrB, pwsA, pwsB;
    if (HASD) {
        pwrA = *(const float4*)&pwr[(2 * mp) * 16 + quad * 4];
        pwrB = *(const float4*)&pwr[(2 * mp + 1) * 16 + quad * 4];
        pwsA = *(const float4*)&pws[(2 * mp) * 16 + quad * 4];
        pwsB = *(const float4*)&pws[(2 * mp + 1) * 16 + quad * 4];
    }
    __syncthreads();   // sM visible

    // ---- phase B: transposed conv, pure LDS operands
    float ps0[4] = {0, 0, 0, 0}, ps1[4] = {0, 0, 0, 0};

#pragma unroll
    for (int nt = 0; nt < NTPB; ++nt) {
        int lo = nt * 16 + l15;
        long go = gbase + nbase + lo;
        floatx4 a0 = {b40.x, b40.y, b40.z, b40.w};
        floatx4 a1 = {b41.x, b41.y, b41.z, b41.w};
#pragma unroll
        for (int k = 0; k < 4; ++k) {
            short8 B0 = *(const short8*)&sM[lo * MSTR + k * 32 + quad * 8];
            a0 = __builtin_amdgcn_mfma_f32_16x16x32_bf16(Wr8[0][k], B0, a0, 0, 0, 0);
            a1 = __builtin_amdgcn_mfma_f32_16x16x32_bf16(Wr8[1][k], B0, a1, 0, 0, 0);
        }
#pragma unroll
        for (int k = 0; k < 4; ++k) {
            short8 B1 = *(const short8*)&sX[lo * MSTR + k * 32 + quad * 8];
            a0 = __builtin_amdgcn_mfma_f32_16x16x32_bf16(Ws8[0][k], B1, a0, 0, 0, 0);
            a1 = __builtin_amdgcn_mfma_f32_16x16x32_bf16(Ws8[1][k], B1, a1, 0, 0, 0);
        }
        bool liv = av[nt] != 0.0f;
        float v0r[4], v1r[4];
#pragma unroll
        for (int rr = 0; rr < 4; ++rr) {
            v0r[rr] = fmaxf(a0[rr], 0.0f);
            v1r[rr] = fmaxf(a1[rr], 0.0f);
            if (liv) { ps0[rr] += v0r[rr]; ps1[rr] += v1r[rr]; }
            if (!liv) { v0r[rr] = 0.0f; v1r[rr] = 0.0f; }
        }
        if (!LAST) {
            // tiled feature-major store: per quad the 4 rr-stores are contiguous 128 B
            unsigned short* orow = &xtout[(gt0 + nt) * TSTR];
#pragma unroll
            for (int rr = 0; rr < 4; ++rr) {
                orow[((2 * mp) * 16 + quad * 4 + rr) * 16 + l15] = f2b(v0r[rr]);
                orow[((2 * mp + 1) * 16 + quad * 4 + rr) * 16 + l15] = f2b(v1r[rr]);
            }
        }
        // pool-score partial dots (wave's 32 features), reduce over quads, store per-mp slot
        if (HASD) {
            float pr = v0r[0]*pwrA.x + v0r[1]*pwrA.y + v0r[2]*pwrA.z + v0r[3]*pwrA.w
                     + v1r[0]*pwrB.x + v1r[1]*pwrB.y + v1r[2]*pwrB.z + v1r[3]*pwrB.w;
            float pd = v0r[0]*pwsA.x + v0r[1]*pwsA.y + v0r[2]*pwsA.z + v0r[3]*pwsA.w
                     + v1r[0]*pwsB.x + v1r[1]*pwsB.y + v1r[2]*pwsB.z + v1r[3]*pwsB.w;
            pr += __shfl_xor(pr, 16); pr += __shfl_xor(pr, 32);
            pd += __shfl_xor(pd, 16); pd += __shfl_xor(pd, 32);
            if (quad == 0) {
                float2 st = {pr, pd};
                *(float2*)&dd[go * 8 + mp * 2] = st;
            }
        }
    }
    // fused readout: reduce over l15 (node lanes), atomic into hcat
#pragma unroll
    for (int rr = 0; rr < 4; ++rr) {
        float v = ps0[rr];
        v += __shfl_xor(v, 1); v += __shfl_xor(v, 2); v += __shfl_xor(v, 4); v += __shfl_xor(v, 8);
        float u = ps1[rr];
        u += __shfl_xor(u, 1); u += __shfl_xor(u, 2); u += __shfl_xor(u, 4); u += __shfl_xor(u, 8);
        if (l15 == 0) {
            atomicAdd(&hcat[g * (5 * HD) + layer * HD + (2 * mp) * 16 + quad * 4 + rr], v);
            atomicAdd(&hcat[g * (5 * HD) + layer * HD + (2 * mp + 1) * 16 + quad * 4 + rr], u);
        }
    }
}

// ---------------- pool v4 (512 thr): dense-adjacency neighbor sums; top-K with
//  parallel tie-break (bitmask + popcount prefix); mult/alive/rliv
__global__ __launch_bounds__(512) void k_pool2(
    const float* __restrict__ dd, const unsigned int* __restrict__ A,
    float* __restrict__ multg, float* __restrict__ alive, float* __restrict__ rliv,
    const float* __restrict__ pb, int K)
{
    __shared__ float str[NPG0];
    __shared__ float stsb[NPG0];
    __shared__ float sal[NPG0];
    __shared__ float s[512];
    __shared__ float sc[NPG0];
    __shared__ float kf[NPG0];
    __shared__ unsigned char keep[NPG0];
    __shared__ unsigned int tmsk[13];   // 416-bit tie mask
    __shared__ int cnt_gt;
    int g = blockIdx.x, t = threadIdx.x;
    long nb = (long)g * NPG0;
    float pbv = pb[0];

    for (int n = t; n < NPG0; n += 512) {
        const float* dp = &dd[(nb + n) * 8];
        float4 da = *(const float4*)dp;
        float4 db = *(const float4*)(dp + 4);
        str[n] = da.x + da.z + db.x + db.z;          // x @ p_wr
        stsb[n] = da.y + da.w + db.y + db.w + pbv;   // x @ p_ws + b
        sal[n] = alive[nb + n];
    }
    if (t == 0) cnt_gt = 0;
    if (t < 13) tmsk[t] = 0u;
    __syncthreads();

    for (int n = t; n < 512; n += 512) {
        float v = -INFINITY;
        if (n < NPG0 && sal[n] != 0.0f) {
            const uint4* Ar = (const uint4*)(A + ((long)g * NPG0 + n) * 52);
            float ssum = 0.0f;
#pragma unroll
            for (int c = 0; c < 13; ++c) {
                uint4 q = Ar[c];
                ssum += nibdot(q.x, &str[c * 32]);
                ssum += nibdot(q.y, &str[c * 32 + 8]);
                ssum += nibdot(q.z, &str[c * 32 + 16]);
                ssum += nibdot(q.w, &str[c * 32 + 24]);
            }
            v = ssum * rliv[nb + n] + stsb[n];
        }
        s[n] = v;
        if (n < NPG0) sc[n] = v;
    }
    __syncthreads();

    for (int ksz = 2; ksz <= 512; ksz <<= 1) {
        for (int jsz = ksz >> 1; jsz >= 1; jsz >>= 1) {
            for (int i = t; i < 512; i += 512) {
                int ixj = i ^ jsz;
                if (ixj > i) {
                    float a = s[i], c = s[ixj];
                    bool up = ((i & ksz) == 0);
                    if ((a > c) == up) { s[i] = c; s[ixj] = a; }
                }
            }
            __syncthreads();
        }
    }
    float thr = s[512 - K];
    // count strict-greater and record ties in the bitmask (one pass)
    for (int n = t; n < NPG0; n += 512) {
        if (sc[n] > thr) atomicAdd(&cnt_gt, 1);
        else if (sc[n] == thr) atomicOr(&tmsk[n >> 5], 1u << (n & 31));
    }
    __syncthreads();
    int m = K - cnt_gt;
    // parallel tie-break: accept ties with rank (by index) < m — identical to serial scan
    for (int n = t; n < NPG0; n += 512) {
        bool kp = sc[n] > thr;
        if (!kp && sc[n] == thr) {
            int w = n >> 5;
            int rank = __popc(tmsk[w] & ((1u << (n & 31)) - 1u));
            for (int j = 0; j < w; ++j) rank += __popc(tmsk[j]);
            kp = rank < m;
        }
        keep[n] = kp ? 1 : 0;
    }
    __syncthreads();
    for (int n = t; n < NPG0; n += 512) {
        multg[nb + n] = keep[n] ? tanhf(sc[n]) : 0.0f;
        alive[nb + n] = keep[n] ? 1.0f : 0.0f;
        kf[n] = keep[n] ? 1.0f : 0.0f;
    }
    __syncthreads();
    for (int n = t; n < NPG0; n += 512) {
        const uint4* Ar = (const uint4*)(A + ((long)g * NPG0 + n) * 52);
        float ssum = 0.0f;
#pragma unroll
        for (int c = 0; c < 13; ++c) {
            uint4 q = Ar[c];
            ssum += nibdot(q.x, &kf[c * 32]);
            ssum += nibdot(q.y, &kf[c * 32 + 8]);
            ssum += nibdot(q.z, &kf[c * 32 + 16]);
            ssum += nibdot(q.w, &kf[c * 32 + 24]);
        }
        rliv[nb + n] = 1.0f / fmaxf(ssum, 1.0f);
    }
}

// ---------------- final MLP + log_softmax (hcat holds SUMS; divide here)
__global__ __launch_bounds__(128) void k_mlp(const float* __restrict__ h, const float* __restrict__ w1,
    const float* __restrict__ b1, const float* __restrict__ w2,
    const float* __restrict__ b2, float* __restrict__ out) {
    __shared__ float h1[HD];
    __shared__ float red[HD];
    __shared__ float lg[2];
    const float inv[5] = {1.0f/400.0f, 1.0f/400.0f, 1.0f/320.0f, 1.0f/320.0f, 1.0f/256.0f};
    int g = blockIdx.x, j = threadIdx.x;
    const float* hg = &h[g * (5 * HD)];
    float acc = b1[j];
    for (int k = 0; k < 5 * HD; k++) acc += hg[k] * inv[k >> 7] * w1[k * HD + j];
    h1[j] = fmaxf(acc, 0.0f);
    __syncthreads();
    for (int c = 0; c < 2; c++) {
        red[j] = h1[j] * w2[j * 2 + c];
        __syncthreads();
        for (int st = 64; st > 0; st >>= 1) {
            if (j < st) red[j] += red[j + st];
            __syncthreads();
        }
        if (j == 0) lg[c] = red[0] + b2[c];
        __syncthreads();
    }
    if (j == 0) {
        float l0 = lg[0], l1 = lg[1];
        float m = fmaxf(l0, l1);
        float lse = m + logf(expf(l0 - m) + expf(l1 - m));
        out[g * 2 + 0] = l0 - lse;
        out[g * 2 + 1] = l1 - lse;
    }
}

extern "C" void kernel_launch(void* const* d_in, const int* in_sizes, int n_in,
                              void* d_out, int out_size, void* d_ws, size_t ws_size,
                              hipStream_t stream) {
    const float* x_in   = (const float*)d_in[0];
    const int*   eidx   = (const int*)d_in[1];
    const int*   e_src  = eidx;
    const int*   e_dst  = eidx + NE;
    const float* c1_wr  = (const float*)d_in[3];
    const float* c1_ws  = (const float*)d_in[4];
    const float* c1_b   = (const float*)d_in[5];
    const float* cs_wr  = (const float*)d_in[6];
    const float* cs_ws  = (const float*)d_in[7];
    const float* cs_b   = (const float*)d_in[8];
    const float* p_wr   = (const float*)d_in[9];
    const float* p_ws   = (const float*)d_in[10];
    const float* p_b    = (const float*)d_in[11];
    const float* l1_w   = (const float*)d_in[12];
    const float* l1_b   = (const float*)d_in[13];
    const float* l2_w   = (const float*)d_in[14];
    const float* l2_b   = (const float*)d_in[15];
    float* out = (float*)d_out;

    char* ws = (char*)d_ws;
    size_t off = 0;
    float* alive = (float*)(ws + off);           off += (size_t)NN * 4;
    float* rliv  = (float*)(ws + off);           off += (size_t)NN * 4;
    float* hcat  = (float*)(ws + off);           off += (size_t)BGR * 5 * HD * 4;
    unsigned short* wbt = (unsigned short*)(ws + off); off += (size_t)10 * HD * HD * 2;
    unsigned int* Amat = (unsigned int*)(ws + off);    off += (size_t)NN * 52 * 4;
    unsigned short* xtA = (unsigned short*)(ws + off); off += ((size_t)BGR * GSTR + TSTR) * 2;
    unsigned short* xtB = (unsigned short*)(ws + off); off += ((size_t)BGR * GSTR + TSTR) * 2;
    float* dd    = (float*)(ws + off);           off += (size_t)NN * 8 * 4;
    float* multg = (float*)(ws + off);           off += (size_t)NN * 4;

    hipMemsetAsync(hcat, 0, (size_t)BGR * 5 * HD * 4, stream);
    // zero one tile tail: k=12/quad>=2 A-frag reads of the LAST graph hit tile 6400
    hipMemsetAsync(xtA + (size_t)BGR * GSTR, 0, TSTR * 2, stream);
    hipMemsetAsync(xtB + (size_t)BGR * GSTR, 0, TSTR * 2, stream);

    k_graph2<<<BGR, 512, 0, stream>>>(e_src, e_dst, Amat, alive, rliv);
    k_wcvt<<<dim3(64, 10), 256, 0, stream>>>(c1_wr, c1_ws, cs_wr, cs_ws, wbt);
    k_xt0<<<dim3(200, 32), 512, 0, stream>>>(x_in, xtB);

    unsigned short* bt_wr[5] = { wbt + 0 * HD * HD, wbt + 2 * HD * HD, wbt + 3 * HD * HD, wbt + 4 * HD * HD, wbt + 5 * HD * HD };
    unsigned short* bt_ws[5] = { wbt + 1 * HD * HD, wbt + 6 * HD * HD, wbt + 7 * HD * HD, wbt + 8 * HD * HD, wbt + 9 * HD * HD };
    const unsigned char* Am8 = (const unsigned char*)Amat;

    // L0 (conv1): xtB -> xtA
    k_layer14<false, false><<<dim3(BGR, NTPB), 256, 0, stream>>>(
        xtB, xtA, Am8, alive, rliv,
        bt_wr[0], bt_ws[0], c1_b, hcat, 0, nullptr, nullptr, nullptr);
    // L1 (convs[0]) + pool0 dots: xtA -> xtB
    k_layer14<true, false><<<dim3(BGR, NTPB), 256, 0, stream>>>(
        xtA, xtB, Am8, alive, rliv,
        bt_wr[1], bt_ws[1], cs_b + 0 * HD, hcat, 1, p_wr + 0 * HD, p_ws + 0 * HD, dd);
    // pool 0 (K=320)
    k_pool2<<<BGR, 512, 0, stream>>>(dd, Amat, multg, alive, rliv, p_b + 0, 320);
    k_scale<<<SCGRID, 256, 0, stream>>>(xtB, multg);
    // L2 (convs[1]): xtB -> xtA
    k_layer14<false, false><<<dim3(BGR, NTPB), 256, 0, stream>>>(
        xtB, xtA, Am8, alive, rliv,
        bt_wr[2], bt_ws[2], cs_b + 1 * HD, hcat, 2, nullptr, nullptr, nullptr);
    // L3 (convs[2]) + pool1 dots: xtA -> xtB
    k_layer14<true, false><<<dim3(BGR, NTPB), 256, 0, stream>>>(
        xtA, xtB, Am8, alive, rliv,
        bt_wr[3], bt_ws[3], cs_b + 2 * HD, hcat, 3, p_wr + 1 * HD, p_ws + 1 * HD, dd);
    // pool 1 (K=256)
    k_pool2<<<BGR, 512, 0, stream>>>(dd, Amat, multg, alive, rliv, p_b + 1, 256);
    k_scale<<<SCGRID, 256, 0, stream>>>(xtB, multg);
    // L4 (convs[3], no x output): xtB -> (readout only)
    k_layer14<false, true><<<dim3(BGR, NTPB), 256, 0, stream>>>(
        xtB, nullptr, Am8, alive, rliv,
        bt_wr[4], bt_ws[4], cs_b + 3 * HD, hcat, 4, nullptr, nullptr, nullptr);
    // MLP head
    k_mlp<<<BGR, HD, 0, stream>>>(hcat, l1_w, l1_b, l2_w, l2_b, out);
}